// Round 10
// baseline (286.826 us; speedup 1.0000x reference)
//
#include <hip/hip_runtime.h>
#include <math.h>

// Problem constants: B=4, NF=64, H=W=128, K=9
// d_in order: nbr, ref, w1, b1, w2, b2, w3, b3, w_off, b_off, w_dcn, b_dcn
// d_out: feat [4,64,128,128] | offset [4,18,128,128] | mask [4,9,128,128]

typedef _Float16 h8 __attribute__((ext_vector_type(8)));  // 8 f16 (4 VGPRs)
typedef _Float16 h4 __attribute__((ext_vector_type(4)));  // 4 f16 (2 VGPRs)
typedef _Float16 h2 __attribute__((ext_vector_type(2)));  // packed f16 pair
typedef float f4 __attribute__((ext_vector_type(4)));     // 4 fp32 acc

// ================ merged setup: weight prep + border zero + input prep ================
// roles by blockIdx: [0,792) wprep, [792,1050) border zero, [1050,3098) NCHW->padded NHWC f16
__global__ __launch_bounds__(256) void setup_kernel(
    const float* __restrict__ nbr, const float* __restrict__ refp,
    const float* __restrict__ w1, const float* __restrict__ w2,
    const float* __restrict__ w3, const float* __restrict__ w_off,
    const float* __restrict__ w_dcn,
    _Float16* __restrict__ X1, _Float16* __restrict__ X2,
    _Float16* __restrict__ B64, _Float16* __restrict__ C64,
    _Float16* __restrict__ wF1, _Float16* __restrict__ wF2,
    _Float16* __restrict__ wF3, _Float16* __restrict__ wFo,
    _Float16* __restrict__ wFd) {
  __shared__ float t[64 * 65];
  int bid = blockIdx.x;
  int tid = threadIdx.x;
  if (bid < 792) {
    // ---- weight prep (f16)
    int i = bid * 256 + tid;
    if (i < 73728) {                       // w1: global chunk 0..3 (128 IC)
      int j = i;
      int icw = j & 31; int t1 = j >> 5; int oc = t1 & 63; int t2 = t1 >> 6;
      int ch = t2 & 3; int tap = t2 >> 2; int ic = ch * 32 + icw;
      wF1[j] = (_Float16)w1[(oc * 128 + ic) * 9 + tap];
    } else if (i < 110592) {               // w2
      int j = i - 73728;
      int icw = j & 31; int t1 = j >> 5; int oc = t1 & 63; int t2 = t1 >> 6;
      int ch = t2 & 1; int tap = t2 >> 1; int ic = ch * 32 + icw;
      wF2[j] = (_Float16)w2[(oc * 64 + ic) * 9 + tap];
    } else if (i < 147456) {               // w3
      int j = i - 110592;
      int icw = j & 31; int t1 = j >> 5; int oc = t1 & 63; int t2 = t1 >> 6;
      int ch = t2 & 1; int tap = t2 >> 1; int ic = ch * 32 + icw;
      wF3[j] = (_Float16)w3[(oc * 64 + ic) * 9 + tap];
    } else if (i < 165888) {               // w_off padded to 32 oc
      int j = i - 147456;
      int icw = j & 31; int t1 = j >> 5; int oc = t1 & 31; int t2 = t1 >> 5;
      int ch = t2 & 1; int tap = t2 >> 1; int ic = ch * 32 + icw;
      float v = (oc < 27) ? w_off[(oc * 64 + ic) * 9 + tap] : 0.f;
      wFo[j] = (_Float16)v;
    } else if (i < 202752) {               // w_dcn -> [oc][tap*64+c]
      int j = i - 165888;
      int oc = j / 576; int r = j - oc * 576; int tap = r >> 6; int c = r & 63;
      wFd[j] = (_Float16)w_dcn[(oc * 64 + c) * 9 + tap];
    }
    return;
  }
  if (bid < 1050) {
    // ---- zero pad borders of X1, X2, B64, C64 (all CH=64)
    int i = (bid - 792) * 256 + tid;       // 66048 = 4 buf * 4 b * 516 px * 8 chunks
    int bufi = i / 16512;
    int j = i - bufi * 16512;
    int b = j / 4128;
    int r = j - b * 4128;
    int p = r >> 3; int cg = r & 7;
    int row, col;
    if (p < 130)      { row = 0;   col = p; }
    else if (p < 260) { row = 129; col = p - 130; }
    else if (p < 388) { row = 1 + (p - 260); col = 0; }
    else              { row = 1 + (p - 388); col = 129; }
    _Float16* dst = (bufi == 0) ? X1 : (bufi == 1) ? X2 : (bufi == 2) ? B64 : C64;
    uint4 z; z.x = z.y = z.z = z.w = 0u;
    *(uint4*)(dst + ((size_t)(b * 130 + row) * 130 + col) * 64 + cg * 8) = z;
    return;
  }
  // ---- input prep: fp32 NCHW -> padded NHWC f16 (64-px half-rows)
  int j = bid - 1050;                      // 2048 = 2 src * 4 b * 128 y * 2 half
  int half = j & 1;
  int y = (j >> 1) & 127;
  int b = (j >> 8) & 3;
  int src = j >> 10;
  const float* sp = src ? refp : nbr;
  _Float16* dst = src ? X2 : X1;
  for (int l = tid; l < 64 * 64; l += 256) {
    int c = l >> 6, gx = l & 63;
    t[c * 65 + gx] = sp[(((size_t)b * 64 + c) << 14) + (y << 7) + half * 64 + gx];
  }
  __syncthreads();
  unsigned* dstU = (unsigned*)dst;
  for (int l = tid; l < 64 * 32; l += 256) {
    int pxl = l >> 5, c2 = l & 31;
    union { _Float16 h[2]; unsigned u; } pk;
    pk.h[0] = (_Float16)t[(2 * c2) * 65 + pxl];
    pk.h[1] = (_Float16)t[(2 * c2 + 1) * 65 + pxl];
    dstU[((size_t)(b * 130 + y + 1) * 130 + 1 + half * 64 + pxl) * 32 + c2] = pk.u;
  }
}

// ================ f16 MFMA conv3x3 + bias + lrelu -> padded NHWC f16 ================
// Half-row blocks for occupancy: grid 1024 (= 8 xcd * 16 ystrip * 2 half * 4 b),
// 4 waves, wave tile M=64(oc) x N=16(px) -> 4096 waves = 16 waves/CU (vs 8 before).
// Inputs padded NHWC f16 [B][130][130][64]; conv1 reads two (concat via SPLIT).
// W: f16 slices [(tap*NCH+c)*64+oc][32].
// mfma_f32_16x16x32_f16 (lane L, lm=L&15, lq=L>>4):
//   a[j]=A[m=lm][k=lq*8+j]  b[j]=B[k=lq*8+j][n=lm]  d[r]=D[row=lq*4+r][col=lm]
template <int NCH, bool SPLIT>
__global__ __launch_bounds__(256, 4) void conv3x3_f16_kernel(
    const _Float16* __restrict__ X1, const _Float16* __restrict__ X2,
    const _Float16* __restrict__ W, const float* __restrict__ bias,
    _Float16* __restrict__ outP) {
  int tid = threadIdx.x;
  int wv = tid >> 6, L = tid & 63;
  int lm = L & 15, lq = L >> 4;
  int bid = blockIdx.x;                 // 1024 = 8 xcd * (16 ystrip * 2 half * 4 b)
  int xcd = bid & 7, j = bid >> 3;
  int y = (xcd << 4) | (j & 15);
  int half = (j >> 4) & 1;
  int b = j >> 5;
  int px0 = half * 64 + wv * 16;

  f4 acc[4];
#pragma unroll
  for (int i = 0; i < 4; ++i) acc[i] = (f4)0.f;

  for (int c = 0; c < NCH; ++c) {
    const _Float16* src = (SPLIT && c >= 2) ? X2 : X1;
    int cl = SPLIT ? (c & 1) : c;
#pragma unroll
    for (int tap = 0; tap < 9; ++tap) {
      const int dy = tap / 3 - 1, dx = tap % 3 - 1;
      const _Float16* xb = src + ((size_t)((b * 130 + (y + 1 + dy)) * 130) + (1 + dx) + px0) * 64
                               + cl * 32 + lq * 8;
      h8 b0 = *(const h8*)(xb + lm * 64);
      const _Float16* wp = W + (size_t)((tap * NCH + c) * 64) * 32 + lm * 32 + lq * 8;
      h8 a0 = *(const h8*)(wp);
      h8 a1 = *(const h8*)(wp + 512);
      h8 a2 = *(const h8*)(wp + 1024);
      h8 a3 = *(const h8*)(wp + 1536);
      acc[0] = __builtin_amdgcn_mfma_f32_16x16x32_f16(a0, b0, acc[0], 0, 0, 0);
      acc[1] = __builtin_amdgcn_mfma_f32_16x16x32_f16(a1, b0, acc[1], 0, 0, 0);
      acc[2] = __builtin_amdgcn_mfma_f32_16x16x32_f16(a2, b0, acc[2], 0, 0, 0);
      acc[3] = __builtin_amdgcn_mfma_f32_16x16x32_f16(a3, b0, acc[3], 0, 0, 0);
    }
  }
  // epilogue: bias + lrelu, pack 4 consecutive oc -> 8 B store, padded NHWC f16
  const size_t obase = ((size_t)(b * 130 + (y + 1)) * 130 + 1) * 64;
  int px = px0 + lm;
#pragma unroll
  for (int mt = 0; mt < 4; ++mt) {
    h4 pk;
#pragma unroll
    for (int r = 0; r < 4; ++r) {
      int oc = mt * 16 + lq * 4 + r;
      float v = acc[mt][r] + bias[oc];
      v = (v >= 0.f) ? v : 0.1f * v;
      pk[r] = (_Float16)v;
    }
    *(h4*)(outP + obase + (size_t)px * 64 + mt * 16 + lq * 4) = pk;
  }
}

// ================ f16 MFMA conv_off: 64 -> 27(pad 32), fused 15*tanh / sigmoid ========
__global__ __launch_bounds__(256, 4) void conv_off_f16_kernel(
    const _Float16* __restrict__ X, const _Float16* __restrict__ W,
    const float* __restrict__ bias, float* __restrict__ off_out,
    float* __restrict__ mask_out) {
  int tid = threadIdx.x;
  int wv = tid >> 6, L = tid & 63;
  int lm = L & 15, lq = L >> 4;
  int bid = blockIdx.x;
  int xcd = bid & 7, j = bid >> 3;
  int y = (xcd << 4) | (j & 15);
  int b = j >> 4;
  int px0 = wv * 32;

  f4 acc[2][2];
#pragma unroll
  for (int i = 0; i < 2; ++i)
#pragma unroll
    for (int n = 0; n < 2; ++n) acc[i][n] = (f4)0.f;

  for (int c = 0; c < 2; ++c) {
#pragma unroll
    for (int tap = 0; tap < 9; ++tap) {
      const int dy = tap / 3 - 1, dx = tap % 3 - 1;
      const _Float16* xb = X + ((size_t)((b * 130 + (y + 1 + dy)) * 130) + (1 + dx) + px0) * 64
                             + c * 32 + lq * 8;
      h8 b0 = *(const h8*)(xb + lm * 64);
      h8 b1 = *(const h8*)(xb + (16 + lm) * 64);
      const _Float16* wp = W + (size_t)((tap * 2 + c) * 32 + lm) * 32 + lq * 8;
      h8 a0 = *(const h8*)(wp);
      h8 a1 = *(const h8*)(wp + 512);
      acc[0][0] = __builtin_amdgcn_mfma_f32_16x16x32_f16(a0, b0, acc[0][0], 0, 0, 0);
      acc[1][0] = __builtin_amdgcn_mfma_f32_16x16x32_f16(a1, b0, acc[1][0], 0, 0, 0);
      acc[0][1] = __builtin_amdgcn_mfma_f32_16x16x32_f16(a0, b1, acc[0][1], 0, 0, 0);
      acc[1][1] = __builtin_amdgcn_mfma_f32_16x16x32_f16(a1, b1, acc[1][1], 0, 0, 0);
    }
  }
#pragma unroll
  for (int mt = 0; mt < 2; ++mt)
#pragma unroll
    for (int nt = 0; nt < 2; ++nt) {
      int px = px0 + nt * 16 + lm;
      int hw = (y << 7) + px;
#pragma unroll
      for (int r = 0; r < 4; ++r) {
        int oc = mt * 16 + lq * 4 + r;
        if (oc < 18) {
          float v = acc[mt][nt][r] + bias[oc];
          off_out[((b * 18 + oc) << 14) + hw] = 15.f * tanhf(v);
        } else if (oc < 27) {
          float v = acc[mt][nt][r] + bias[oc];
          mask_out[((b * 9 + (oc - 18)) << 14) + hw] = 1.f / (1.f + expf(-v));
        }
      }
    }
}

// ================ DCN (round-8 proven): sample (8 lanes/task, pk-f16 blend) -> LDS -> MFMA
// Xp: PADDED NHWC f16 [B][130][130][64] (= X1); wD: f16 [oc][tap*64+c].
// Block = 32 px (quarter row), 128 threads (2 waves). LDS S[32][328].
__global__ __launch_bounds__(128, 4) void dcn_mfma_kernel(
    const _Float16* __restrict__ Xp, const float* __restrict__ off,
    const float* __restrict__ msk, const _Float16* __restrict__ wD,
    const float* __restrict__ bias, float* __restrict__ out) {
  __shared__ _Float16 S[32 * 328];
  int tid = threadIdx.x;
  int wv = tid >> 6, L = tid & 63;
  int lm = L & 15, lq = L >> 4;
  int t8 = L >> 3, c8 = L & 7;
  int g = blockIdx.x;                 // 2048 = 4 b * 128 y * 4 quarter
  int q = g & 3;
  int y = (g >> 2) & 127;
  int b = g >> 9;
  int pxq0 = q * 32;

  f4 acc[4];
#pragma unroll
  for (int i = 0; i < 4; ++i) acc[i] = (f4)0.f;

  for (int p = 0; p < 2; ++p) {
    const int tap0 = p ? 5 : 0;
    const int TAPS = p ? 4 : 5;
    __syncthreads();
    // ---- sampling: 8 lanes per (px, tap) task; 16 task-groups per iteration
    const int NT = TAPS * 32;
    for (int u = wv * 8 + t8; u < NT; u += 16) {
      int px = u & 31;
      int tl = u >> 5;
      int k = tap0 + tl;
      int wg = pxq0 + px;
      int hw = (y << 7) + wg;
      int kr = k / 3;
      float oy = off[((b * 18 + 2 * k) << 14) + hw];
      float ox = off[((b * 18 + 2 * k + 1) << 14) + hw];
      float m = msk[((b * 9 + k) << 14) + hw];
      float py = (float)(y + kr - 1) + oy;
      float pxf = (float)(wg + (k - kr * 3) - 1) + ox;
      float fy = floorf(py), fx = floorf(pxf);
      float wy = py - fy, wx = pxf - fx;
      int y0 = (int)fy, x0 = (int)fx;
      int y1 = y0 + 1, x1 = x0 + 1;
      float vy0 = ((unsigned)y0 < 128u) ? 1.f : 0.f;
      float vy1 = ((unsigned)y1 < 128u) ? 1.f : 0.f;
      float vx0 = ((unsigned)x0 < 128u) ? 1.f : 0.f;
      float vx1 = ((unsigned)x1 < 128u) ? 1.f : 0.f;
      float ey = 1.f - wy, ex = 1.f - wx;
      _Float16 w00 = (_Float16)(ey * ex * m * vy0 * vx0);
      _Float16 w01 = (_Float16)(ey * wx * m * vy0 * vx1);
      _Float16 w10 = (_Float16)(wy * ex * m * vy1 * vx0);
      _Float16 w11 = (_Float16)(wy * wx * m * vy1 * vx1);
      h2 W00 = {w00, w00}, W01 = {w01, w01}, W10 = {w10, w10}, W11 = {w11, w11};
      int y0c = min(max(y0, 0), 127) + 1, y1c = min(max(y1, 0), 127) + 1;
      int x0c = min(max(x0, 0), 127) + 1, x1c = min(max(x1, 0), 127) + 1;
      int rb = b * 130;
      h8 v00 = *(const h8*)(Xp + ((size_t)((rb + y0c) * 130 + x0c) << 6) + c8 * 8);
      h8 v01 = *(const h8*)(Xp + ((size_t)((rb + y0c) * 130 + x1c) << 6) + c8 * 8);
      h8 v10 = *(const h8*)(Xp + ((size_t)((rb + y1c) * 130 + x0c) << 6) + c8 * 8);
      h8 v11 = *(const h8*)(Xp + ((size_t)((rb + y1c) * 130 + x1c) << 6) + c8 * 8);
      h8 o;
#pragma unroll
      for (int j2 = 0; j2 < 4; ++j2) {
        h2 a = {v00[2 * j2], v00[2 * j2 + 1]};
        h2 bb = {v01[2 * j2], v01[2 * j2 + 1]};
        h2 cc = {v10[2 * j2], v10[2 * j2 + 1]};
        h2 dd = {v11[2 * j2], v11[2 * j2 + 1]};
        h2 r = a * W00;
        r += bb * W01;
        r += cc * W10;
        r += dd * W11;
        o[2 * j2] = r[0];
        o[2 * j2 + 1] = r[1];
      }
      *(h8*)&S[px * 328 + tl * 64 + c8 * 8] = o;
    }
    __syncthreads();
    // ---- MFMA: D[64 oc][32 px] += W[:, kslice] * S (wave covers 16 px)
    const int KS = 2 * TAPS;
    for (int ks = 0; ks < KS; ++ks) {
      int kg = tap0 * 64 + ks * 32;
      const _Float16* wp = wD + (size_t)lm * 576 + kg + lq * 8;
      h8 a0 = *(const h8*)(wp);
      h8 a1 = *(const h8*)(wp + 16 * 576);
      h8 a2 = *(const h8*)(wp + 32 * 576);
      h8 a3 = *(const h8*)(wp + 48 * 576);
      h8 bv = *(const h8*)(&S[(wv * 16 + lm) * 328 + ks * 32 + lq * 8]);
      acc[0] = __builtin_amdgcn_mfma_f32_16x16x32_f16(a0, bv, acc[0], 0, 0, 0);
      acc[1] = __builtin_amdgcn_mfma_f32_16x16x32_f16(a1, bv, acc[1], 0, 0, 0);
      acc[2] = __builtin_amdgcn_mfma_f32_16x16x32_f16(a2, bv, acc[2], 0, 0, 0);
      acc[3] = __builtin_amdgcn_mfma_f32_16x16x32_f16(a3, bv, acc[3], 0, 0, 0);
    }
  }
  // epilogue: bias + lrelu, fp32 NCHW
  int px = pxq0 + wv * 16 + lm;
#pragma unroll
  for (int mt = 0; mt < 4; ++mt)
#pragma unroll
    for (int r = 0; r < 4; ++r) {
      int oc = mt * 16 + lq * 4 + r;
      float v = acc[mt][r] + bias[oc];
      v = (v >= 0.f) ? v : 0.1f * v;
      out[(((b << 6) + oc) << 14) + (y << 7) + px] = v;
    }
}

extern "C" void kernel_launch(void* const* d_in, const int* in_sizes, int n_in,
                              void* d_out, int out_size, void* d_ws, size_t ws_size,
                              hipStream_t stream) {
  const float* nbr   = (const float*)d_in[0];
  const float* refp  = (const float*)d_in[1];
  const float* w1    = (const float*)d_in[2];
  const float* b1    = (const float*)d_in[3];
  const float* w2    = (const float*)d_in[4];
  const float* b2    = (const float*)d_in[5];
  const float* w3    = (const float*)d_in[6];
  const float* b3    = (const float*)d_in[7];
  const float* w_off = (const float*)d_in[8];
  const float* b_off = (const float*)d_in[9];
  const float* w_dcn = (const float*)d_in[10];
  const float* b_dcn = (const float*)d_in[11];

  float* outp = (float*)d_out;
  float* feat = outp;                       // 4*64*16384
  float* offp = outp + 4194304;             // 4*18*16384
  float* mskp = outp + 4194304 + 1179648;   // 4*9*16384

  // ws layout: four padded NHWC f16 buffers [4][130][130][64] + f16 weights (~33.4 MiB)
  char* ws = (char*)d_ws;
  const size_t PB = 8652800;                // bytes per padded buffer
  _Float16* X1  = (_Float16*)ws;            // nbr padded (conv1 in + DCN sample src)
  _Float16* X2  = (_Float16*)(ws + PB);     // ref padded
  _Float16* B64 = (_Float16*)(ws + 2 * PB); // conv1 out / conv3 out
  _Float16* C64 = (_Float16*)(ws + 3 * PB); // conv2 out
  char* p = ws + 4 * PB;
  _Float16* wF1 = (_Float16*)p;  p += (size_t)73728 * 2;
  _Float16* wF2 = (_Float16*)p;  p += (size_t)36864 * 2;
  _Float16* wF3 = (_Float16*)p;  p += (size_t)36864 * 2;
  _Float16* wFo = (_Float16*)p;  p += (size_t)18432 * 2;
  _Float16* wFd = (_Float16*)p;

  // 6 dispatches total
  setup_kernel<<<dim3(3098), 256, 0, stream>>>(nbr, refp, w1, w2, w3, w_off, w_dcn,
                                               X1, X2, B64, C64, wF1, wF2, wF3, wFo, wFd);
  conv3x3_f16_kernel<4, true><<<dim3(1024), 256, 0, stream>>>(X1, X2, wF1, b1, B64);
  conv3x3_f16_kernel<2, false><<<dim3(1024), 256, 0, stream>>>(B64, B64, wF2, b2, C64);
  conv3x3_f16_kernel<2, false><<<dim3(1024), 256, 0, stream>>>(C64, C64, wF3, b3, B64);
  conv_off_f16_kernel<<<dim3(512), 256, 0, stream>>>(B64, wFo, b_off, offp, mskp);
  dcn_mfma_kernel<<<dim3(2048), 128, 0, stream>>>(X1, offp, mskp, wFd, b_dcn, feat);
}

// Round 11
// 256.542 us; speedup vs baseline: 1.1180x; 1.1180x over previous
//
#include <hip/hip_runtime.h>
#include <math.h>

// Problem constants: B=4, NF=64, H=W=128, K=9
// d_in order: nbr, ref, w1, b1, w2, b2, w3, b3, w_off, b_off, w_dcn, b_dcn
// d_out: feat [4,64,128,128] | offset [4,18,128,128] | mask [4,9,128,128]

typedef _Float16 h8 __attribute__((ext_vector_type(8)));  // 8 f16 (4 VGPRs)
typedef _Float16 h4 __attribute__((ext_vector_type(4)));  // 4 f16 (2 VGPRs)
typedef _Float16 h2 __attribute__((ext_vector_type(2)));  // packed f16 pair
typedef float f4 __attribute__((ext_vector_type(4)));     // 4 fp32 acc

// ================ merged setup: weight prep + border zero + input prep ================
// roles by blockIdx: [0,792) wprep, [792,1050) border zero, [1050,3098) NCHW->padded NHWC f16
__global__ __launch_bounds__(256) void setup_kernel(
    const float* __restrict__ nbr, const float* __restrict__ refp,
    const float* __restrict__ w1, const float* __restrict__ w2,
    const float* __restrict__ w3, const float* __restrict__ w_off,
    const float* __restrict__ w_dcn,
    _Float16* __restrict__ X1, _Float16* __restrict__ X2,
    _Float16* __restrict__ B64, _Float16* __restrict__ C64,
    _Float16* __restrict__ wF1, _Float16* __restrict__ wF2,
    _Float16* __restrict__ wF3, _Float16* __restrict__ wFo,
    _Float16* __restrict__ wFd) {
  __shared__ float t[64 * 65];
  int bid = blockIdx.x;
  int tid = threadIdx.x;
  if (bid < 792) {
    // ---- weight prep (f16)
    int i = bid * 256 + tid;
    if (i < 73728) {                       // w1: NCH=4 (128 IC)
      int j = i;
      int icw = j & 31; int t1 = j >> 5; int oc = t1 & 63; int t2 = t1 >> 6;
      int ch = t2 & 3; int tap = t2 >> 2; int ic = ch * 32 + icw;
      wF1[j] = (_Float16)w1[(oc * 128 + ic) * 9 + tap];
    } else if (i < 110592) {               // w2
      int j = i - 73728;
      int icw = j & 31; int t1 = j >> 5; int oc = t1 & 63; int t2 = t1 >> 6;
      int ch = t2 & 1; int tap = t2 >> 1; int ic = ch * 32 + icw;
      wF2[j] = (_Float16)w2[(oc * 64 + ic) * 9 + tap];
    } else if (i < 147456) {               // w3
      int j = i - 110592;
      int icw = j & 31; int t1 = j >> 5; int oc = t1 & 63; int t2 = t1 >> 6;
      int ch = t2 & 1; int tap = t2 >> 1; int ic = ch * 32 + icw;
      wF3[j] = (_Float16)w3[(oc * 64 + ic) * 9 + tap];
    } else if (i < 165888) {               // w_off padded to 32 oc
      int j = i - 147456;
      int icw = j & 31; int t1 = j >> 5; int oc = t1 & 31; int t2 = t1 >> 5;
      int ch = t2 & 1; int tap = t2 >> 1; int ic = ch * 32 + icw;
      float v = (oc < 27) ? w_off[(oc * 64 + ic) * 9 + tap] : 0.f;
      wFo[j] = (_Float16)v;
    } else if (i < 202752) {               // w_dcn -> [oc][tap*64+c]
      int j = i - 165888;
      int oc = j / 576; int r = j - oc * 576; int tap = r >> 6; int c = r & 63;
      wFd[j] = (_Float16)w_dcn[(oc * 64 + c) * 9 + tap];
    }
    return;
  }
  if (bid < 1050) {
    // ---- zero pad borders of X1, X2, B64, C64 (all CH=64)
    int i = (bid - 792) * 256 + tid;       // 66048 = 4 buf * 4 b * 516 px * 8 chunks
    int bufi = i / 16512;
    int j = i - bufi * 16512;
    int b = j / 4128;
    int r = j - b * 4128;
    int p = r >> 3; int cg = r & 7;
    int row, col;
    if (p < 130)      { row = 0;   col = p; }
    else if (p < 260) { row = 129; col = p - 130; }
    else if (p < 388) { row = 1 + (p - 260); col = 0; }
    else              { row = 1 + (p - 388); col = 129; }
    _Float16* dst = (bufi == 0) ? X1 : (bufi == 1) ? X2 : (bufi == 2) ? B64 : C64;
    uint4 z; z.x = z.y = z.z = z.w = 0u;
    *(uint4*)(dst + ((size_t)(b * 130 + row) * 130 + col) * 64 + cg * 8) = z;
    return;
  }
  // ---- input prep: fp32 NCHW -> padded NHWC f16 (64-px half-rows)
  int j = bid - 1050;                      // 2048 = 2 src * 4 b * 128 y * 2 half
  int half = j & 1;
  int y = (j >> 1) & 127;
  int b = (j >> 8) & 3;
  int src = j >> 10;
  const float* sp = src ? refp : nbr;
  _Float16* dst = src ? X2 : X1;
  for (int l = tid; l < 64 * 64; l += 256) {
    int c = l >> 6, gx = l & 63;
    t[c * 65 + gx] = sp[(((size_t)b * 64 + c) << 14) + (y << 7) + half * 64 + gx];
  }
  __syncthreads();
  unsigned* dstU = (unsigned*)dst;
  for (int l = tid; l < 64 * 32; l += 256) {
    int pxl = l >> 5, c2 = l & 31;
    union { _Float16 h[2]; unsigned u; } pk;
    pk.h[0] = (_Float16)t[(2 * c2) * 65 + pxl];
    pk.h[1] = (_Float16)t[(2 * c2 + 1) * 65 + pxl];
    dstU[((size_t)(b * 130 + y + 1) * 130 + 1 + half * 64 + pxl) * 32 + c2] = pk.u;
  }
}

// ================ f16 MFMA conv3x3 + bias + lrelu -> padded NHWC f16 ================
// Round-8 proven shape: 512 blocks (8 xcd * 16 ystrip * 4 b), 4 waves, wave M=64 x N=32.
// launch_bounds(256,2): grid limits to 2 blocks/CU anyway; 256-VGPR budget lets the
// compiler hoist loads deep ahead of the MFMAs (was capped at 128 -> shallow pipeline).
// W: f16 slices [(tap*NCH+c)*64+oc][32].
// mfma_f32_16x16x32_f16 (lane L, lm=L&15, lq=L>>4):
//   a[j]=A[m=lm][k=lq*8+j]  b[j]=B[k=lq*8+j][n=lm]  d[r]=D[row=lq*4+r][col=lm]
template <int NCH, bool SPLIT>
__global__ __launch_bounds__(256, 2) void conv3x3_f16_kernel(
    const _Float16* __restrict__ X1, const _Float16* __restrict__ X2,
    const _Float16* __restrict__ W, const float* __restrict__ bias,
    _Float16* __restrict__ outP) {
  int tid = threadIdx.x;
  int wv = tid >> 6, L = tid & 63;
  int lm = L & 15, lq = L >> 4;
  int bid = blockIdx.x;                 // 512 = 8 xcd * 16 ystrip * 4 b
  int xcd = bid & 7, j = bid >> 3;
  int y = (xcd << 4) | (j & 15);
  int b = j >> 4;
  int px0 = wv * 32;

  f4 acc[4][2];
#pragma unroll
  for (int i = 0; i < 4; ++i)
#pragma unroll
    for (int n = 0; n < 2; ++n) acc[i][n] = (f4)0.f;

#pragma unroll
  for (int c = 0; c < NCH; ++c) {
    const _Float16* src = (SPLIT && c >= 2) ? X2 : X1;
    int cl = SPLIT ? (c & 1) : c;
#pragma unroll
    for (int tap = 0; tap < 9; ++tap) {
      const int dy = tap / 3 - 1, dx = tap % 3 - 1;
      const _Float16* xb = src + ((size_t)((b * 130 + (y + 1 + dy)) * 130) + (1 + dx) + px0) * 64
                               + cl * 32 + lq * 8;
      h8 b0 = *(const h8*)(xb + lm * 64);
      h8 b1 = *(const h8*)(xb + (16 + lm) * 64);
      const _Float16* wp = W + (size_t)((tap * NCH + c) * 64) * 32 + lm * 32 + lq * 8;
      h8 a0 = *(const h8*)(wp);
      h8 a1 = *(const h8*)(wp + 512);
      h8 a2 = *(const h8*)(wp + 1024);
      h8 a3 = *(const h8*)(wp + 1536);
      acc[0][0] = __builtin_amdgcn_mfma_f32_16x16x32_f16(a0, b0, acc[0][0], 0, 0, 0);
      acc[1][0] = __builtin_amdgcn_mfma_f32_16x16x32_f16(a1, b0, acc[1][0], 0, 0, 0);
      acc[2][0] = __builtin_amdgcn_mfma_f32_16x16x32_f16(a2, b0, acc[2][0], 0, 0, 0);
      acc[3][0] = __builtin_amdgcn_mfma_f32_16x16x32_f16(a3, b0, acc[3][0], 0, 0, 0);
      acc[0][1] = __builtin_amdgcn_mfma_f32_16x16x32_f16(a0, b1, acc[0][1], 0, 0, 0);
      acc[1][1] = __builtin_amdgcn_mfma_f32_16x16x32_f16(a1, b1, acc[1][1], 0, 0, 0);
      acc[2][1] = __builtin_amdgcn_mfma_f32_16x16x32_f16(a2, b1, acc[2][1], 0, 0, 0);
      acc[3][1] = __builtin_amdgcn_mfma_f32_16x16x32_f16(a3, b1, acc[3][1], 0, 0, 0);
    }
  }
  // epilogue: bias + lrelu, pack 4 consecutive oc -> 8 B store, padded NHWC f16
  const size_t obase = ((size_t)(b * 130 + (y + 1)) * 130 + 1) * 64;
#pragma unroll
  for (int mt = 0; mt < 4; ++mt)
#pragma unroll
    for (int nt = 0; nt < 2; ++nt) {
      int px = px0 + nt * 16 + lm;
      h4 pk;
#pragma unroll
      for (int r = 0; r < 4; ++r) {
        int oc = mt * 16 + lq * 4 + r;
        float v = acc[mt][nt][r] + bias[oc];
        v = (v >= 0.f) ? v : 0.1f * v;
        pk[r] = (_Float16)v;
      }
      *(h4*)(outP + obase + (size_t)px * 64 + mt * 16 + lq * 4) = pk;
    }
}

// ================ FUSED conv_off + DCN. Block = 32 px (quarter row), 128 thr (2 waves).
// Phase 1: conv_off 64->27(pad 32) at this block's 32 px (wave tile M=32 x N=16),
//   fused 15*tanh/sigmoid, write off/mask to d_out AND stash in LDS Soff.
// Phase 2: round-8 proven DCN: sample (8 lanes/task, pk-f16 blend) -> LDS S -> MFMA.
// Xc = conv3 out (padded NHWC); Xs = nbr padded NHWC (sampling source).
__global__ __launch_bounds__(128, 4) void off_dcn_kernel(
    const _Float16* __restrict__ Xc, const _Float16* __restrict__ Xs,
    const _Float16* __restrict__ Wo, const float* __restrict__ bo,
    const _Float16* __restrict__ wD, const float* __restrict__ bd,
    float* __restrict__ off_out, float* __restrict__ mask_out,
    float* __restrict__ out) {
  __shared__ _Float16 S[32 * 328];
  __shared__ float Soff[32][28];        // per px: [0..17] offsets, [18..26] mask
  int tid = threadIdx.x;
  int wv = tid >> 6, L = tid & 63;
  int lm = L & 15, lq = L >> 4;
  int t8 = L >> 3, c8 = L & 7;
  int g = blockIdx.x;                   // 2048 = 4 b * 128 y * 4 quarter
  int q = g & 3;
  int y = (g >> 2) & 127;
  int b = g >> 9;
  int pxq0 = q * 32;

  // ---- phase 1: conv_off for 32 px; wave wv covers px pxq0+wv*16 .. +15
  {
    int px0 = pxq0 + wv * 16;
    f4 oa[2];
    oa[0] = (f4)0.f; oa[1] = (f4)0.f;
#pragma unroll
    for (int c = 0; c < 2; ++c)
#pragma unroll
      for (int tap = 0; tap < 9; ++tap) {
        const int dy = tap / 3 - 1, dx = tap % 3 - 1;
        const _Float16* xb = Xc + ((size_t)((b * 130 + (y + 1 + dy)) * 130) + (1 + dx) + px0) * 64
                                + c * 32 + lq * 8;
        h8 b0 = *(const h8*)(xb + lm * 64);
        const _Float16* wp = Wo + (size_t)((tap * 2 + c) * 32 + lm) * 32 + lq * 8;
        h8 a0 = *(const h8*)(wp);
        h8 a1 = *(const h8*)(wp + 512);
        oa[0] = __builtin_amdgcn_mfma_f32_16x16x32_f16(a0, b0, oa[0], 0, 0, 0);
        oa[1] = __builtin_amdgcn_mfma_f32_16x16x32_f16(a1, b0, oa[1], 0, 0, 0);
      }
    int gpx = px0 + lm;
    int hw = (y << 7) + gpx;
    int lpx = wv * 16 + lm;
#pragma unroll
    for (int mt = 0; mt < 2; ++mt)
#pragma unroll
      for (int r = 0; r < 4; ++r) {
        int oc = mt * 16 + lq * 4 + r;
        if (oc < 18) {
          float v = 15.f * tanhf(oa[mt][r] + bo[oc]);
          off_out[((b * 18 + oc) << 14) + hw] = v;
          Soff[lpx][oc] = v;
        } else if (oc < 27) {
          float v = 1.f / (1.f + expf(-(oa[mt][r] + bo[oc])));
          mask_out[((b * 9 + (oc - 18)) << 14) + hw] = v;
          Soff[lpx][oc] = v;
        }
      }
  }

  // ---- phase 2: DCN
  f4 acc[4];
#pragma unroll
  for (int i = 0; i < 4; ++i) acc[i] = (f4)0.f;

  for (int p = 0; p < 2; ++p) {
    const int tap0 = p ? 5 : 0;
    const int TAPS = p ? 4 : 5;
    __syncthreads();                     // covers Soff (p=0) and S reuse (p=1)
    // sampling: 8 lanes per (px, tap) task; 16 task-groups per iteration
    const int NT = TAPS * 32;
    for (int u = wv * 8 + t8; u < NT; u += 16) {
      int px = u & 31;
      int tl = u >> 5;
      int k = tap0 + tl;
      int wg = pxq0 + px;
      int kr = k / 3;
      float oy = Soff[px][2 * k];
      float ox = Soff[px][2 * k + 1];
      float m = Soff[px][18 + k];
      float py = (float)(y + kr - 1) + oy;
      float pxf = (float)(wg + (k - kr * 3) - 1) + ox;
      float fy = floorf(py), fx = floorf(pxf);
      float wy = py - fy, wx = pxf - fx;
      int y0 = (int)fy, x0 = (int)fx;
      int y1 = y0 + 1, x1 = x0 + 1;
      float vy0 = ((unsigned)y0 < 128u) ? 1.f : 0.f;
      float vy1 = ((unsigned)y1 < 128u) ? 1.f : 0.f;
      float vx0 = ((unsigned)x0 < 128u) ? 1.f : 0.f;
      float vx1 = ((unsigned)x1 < 128u) ? 1.f : 0.f;
      float ey = 1.f - wy, ex = 1.f - wx;
      _Float16 w00 = (_Float16)(ey * ex * m * vy0 * vx0);
      _Float16 w01 = (_Float16)(ey * wx * m * vy0 * vx1);
      _Float16 w10 = (_Float16)(wy * ex * m * vy1 * vx0);
      _Float16 w11 = (_Float16)(wy * wx * m * vy1 * vx1);
      h2 W00 = {w00, w00}, W01 = {w01, w01}, W10 = {w10, w10}, W11 = {w11, w11};
      int y0c = min(max(y0, 0), 127) + 1, y1c = min(max(y1, 0), 127) + 1;
      int x0c = min(max(x0, 0), 127) + 1, x1c = min(max(x1, 0), 127) + 1;
      int rb = b * 130;
      h8 v00 = *(const h8*)(Xs + ((size_t)((rb + y0c) * 130 + x0c) << 6) + c8 * 8);
      h8 v01 = *(const h8*)(Xs + ((size_t)((rb + y0c) * 130 + x1c) << 6) + c8 * 8);
      h8 v10 = *(const h8*)(Xs + ((size_t)((rb + y1c) * 130 + x0c) << 6) + c8 * 8);
      h8 v11 = *(const h8*)(Xs + ((size_t)((rb + y1c) * 130 + x1c) << 6) + c8 * 8);
      h8 o;
#pragma unroll
      for (int j2 = 0; j2 < 4; ++j2) {
        h2 a = {v00[2 * j2], v00[2 * j2 + 1]};
        h2 bb = {v01[2 * j2], v01[2 * j2 + 1]};
        h2 cc = {v10[2 * j2], v10[2 * j2 + 1]};
        h2 dd = {v11[2 * j2], v11[2 * j2 + 1]};
        h2 r = a * W00;
        r += bb * W01;
        r += cc * W10;
        r += dd * W11;
        o[2 * j2] = r[0];
        o[2 * j2 + 1] = r[1];
      }
      *(h8*)&S[px * 328 + tl * 64 + c8 * 8] = o;
    }
    __syncthreads();
    // MFMA: D[64 oc][32 px] += W[:, kslice] * S (wave covers 16 px)
    const int KS = 2 * TAPS;
    for (int ks = 0; ks < KS; ++ks) {
      int kg = tap0 * 64 + ks * 32;
      const _Float16* wp = wD + (size_t)lm * 576 + kg + lq * 8;
      h8 a0 = *(const h8*)(wp);
      h8 a1 = *(const h8*)(wp + 16 * 576);
      h8 a2 = *(const h8*)(wp + 32 * 576);
      h8 a3 = *(const h8*)(wp + 48 * 576);
      h8 bv = *(const h8*)(&S[(wv * 16 + lm) * 328 + ks * 32 + lq * 8]);
      acc[0] = __builtin_amdgcn_mfma_f32_16x16x32_f16(a0, bv, acc[0], 0, 0, 0);
      acc[1] = __builtin_amdgcn_mfma_f32_16x16x32_f16(a1, bv, acc[1], 0, 0, 0);
      acc[2] = __builtin_amdgcn_mfma_f32_16x16x32_f16(a2, bv, acc[2], 0, 0, 0);
      acc[3] = __builtin_amdgcn_mfma_f32_16x16x32_f16(a3, bv, acc[3], 0, 0, 0);
    }
  }
  // epilogue: bias + lrelu, fp32 NCHW
  int px = pxq0 + wv * 16 + lm;
#pragma unroll
  for (int mt = 0; mt < 4; ++mt)
#pragma unroll
    for (int r = 0; r < 4; ++r) {
      int oc = mt * 16 + lq * 4 + r;
      float v = acc[mt][r] + bd[oc];
      v = (v >= 0.f) ? v : 0.1f * v;
      out[(((b << 6) + oc) << 14) + (y << 7) + px] = v;
    }
}

extern "C" void kernel_launch(void* const* d_in, const int* in_sizes, int n_in,
                              void* d_out, int out_size, void* d_ws, size_t ws_size,
                              hipStream_t stream) {
  const float* nbr   = (const float*)d_in[0];
  const float* refp  = (const float*)d_in[1];
  const float* w1    = (const float*)d_in[2];
  const float* b1    = (const float*)d_in[3];
  const float* w2    = (const float*)d_in[4];
  const float* b2    = (const float*)d_in[5];
  const float* w3    = (const float*)d_in[6];
  const float* b3    = (const float*)d_in[7];
  const float* w_off = (const float*)d_in[8];
  const float* b_off = (const float*)d_in[9];
  const float* w_dcn = (const float*)d_in[10];
  const float* b_dcn = (const float*)d_in[11];

  float* outp = (float*)d_out;
  float* feat = outp;                       // 4*64*16384
  float* offp = outp + 4194304;             // 4*18*16384
  float* mskp = outp + 4194304 + 1179648;   // 4*9*16384

  // ws layout: four padded NHWC f16 buffers [4][130][130][64] + f16 weights (~33.4 MiB)
  char* ws = (char*)d_ws;
  const size_t PB = 8652800;                // bytes per padded buffer
  _Float16* X1  = (_Float16*)ws;            // nbr padded (conv1 in + DCN sample src)
  _Float16* X2  = (_Float16*)(ws + PB);     // ref padded
  _Float16* B64 = (_Float16*)(ws + 2 * PB); // conv1 out / conv3 out
  _Float16* C64 = (_Float16*)(ws + 3 * PB); // conv2 out
  char* p = ws + 4 * PB;
  _Float16* wF1 = (_Float16*)p;  p += (size_t)73728 * 2;
  _Float16* wF2 = (_Float16*)p;  p += (size_t)36864 * 2;
  _Float16* wF3 = (_Float16*)p;  p += (size_t)36864 * 2;
  _Float16* wFo = (_Float16*)p;  p += (size_t)18432 * 2;
  _Float16* wFd = (_Float16*)p;

  // 5 dispatches total
  setup_kernel<<<dim3(3098), 256, 0, stream>>>(nbr, refp, w1, w2, w3, w_off, w_dcn,
                                               X1, X2, B64, C64, wF1, wF2, wF3, wFo, wFd);
  conv3x3_f16_kernel<4, true><<<dim3(512), 256, 0, stream>>>(X1, X2, wF1, b1, B64);
  conv3x3_f16_kernel<2, false><<<dim3(512), 256, 0, stream>>>(B64, B64, wF2, b2, C64);
  conv3x3_f16_kernel<2, false><<<dim3(512), 256, 0, stream>>>(C64, C64, wF3, b3, B64);
  off_dcn_kernel<<<dim3(2048), 128, 0, stream>>>(B64, X1, wFo, b_off, wFd, b_dcn,
                                                 offp, mskp, feat);
}

// Round 12
// 253.378 us; speedup vs baseline: 1.1320x; 1.0125x over previous
//
#include <hip/hip_runtime.h>
#include <math.h>

// Problem constants: B=4, NF=64, H=W=128, K=9
// d_in order: nbr, ref, w1, b1, w2, b2, w3, b3, w_off, b_off, w_dcn, b_dcn
// d_out: feat [4,64,128,128] | offset [4,18,128,128] | mask [4,9,128,128]

typedef _Float16 h8 __attribute__((ext_vector_type(8)));  // 8 f16 (4 VGPRs)
typedef _Float16 h4 __attribute__((ext_vector_type(4)));  // 4 f16 (2 VGPRs)
typedef _Float16 h2 __attribute__((ext_vector_type(2)));  // packed f16 pair
typedef float f4 __attribute__((ext_vector_type(4)));     // 4 fp32 acc

// ================ merged setup: weight prep + border zero + input prep ================
__global__ __launch_bounds__(256) void setup_kernel(
    const float* __restrict__ nbr, const float* __restrict__ refp,
    const float* __restrict__ w1, const float* __restrict__ w2,
    const float* __restrict__ w3, const float* __restrict__ w_off,
    const float* __restrict__ w_dcn,
    _Float16* __restrict__ X1, _Float16* __restrict__ X2,
    _Float16* __restrict__ B64, _Float16* __restrict__ C64,
    _Float16* __restrict__ wF1, _Float16* __restrict__ wF2,
    _Float16* __restrict__ wF3, _Float16* __restrict__ wFo,
    _Float16* __restrict__ wFd) {
  __shared__ float t[64 * 65];
  int bid = blockIdx.x;
  int tid = threadIdx.x;
  if (bid < 792) {
    int i = bid * 256 + tid;
    if (i < 73728) {                       // w1: NCH=4 (128 IC)
      int j = i;
      int icw = j & 31; int t1 = j >> 5; int oc = t1 & 63; int t2 = t1 >> 6;
      int ch = t2 & 3; int tap = t2 >> 2; int ic = ch * 32 + icw;
      wF1[j] = (_Float16)w1[(oc * 128 + ic) * 9 + tap];
    } else if (i < 110592) {               // w2
      int j = i - 73728;
      int icw = j & 31; int t1 = j >> 5; int oc = t1 & 63; int t2 = t1 >> 6;
      int ch = t2 & 1; int tap = t2 >> 1; int ic = ch * 32 + icw;
      wF2[j] = (_Float16)w2[(oc * 64 + ic) * 9 + tap];
    } else if (i < 147456) {               // w3
      int j = i - 110592;
      int icw = j & 31; int t1 = j >> 5; int oc = t1 & 63; int t2 = t1 >> 6;
      int ch = t2 & 1; int tap = t2 >> 1; int ic = ch * 32 + icw;
      wF3[j] = (_Float16)w3[(oc * 64 + ic) * 9 + tap];
    } else if (i < 165888) {               // w_off padded to 32 oc
      int j = i - 147456;
      int icw = j & 31; int t1 = j >> 5; int oc = t1 & 31; int t2 = t1 >> 5;
      int ch = t2 & 1; int tap = t2 >> 1; int ic = ch * 32 + icw;
      float v = (oc < 27) ? w_off[(oc * 64 + ic) * 9 + tap] : 0.f;
      wFo[j] = (_Float16)v;
    } else if (i < 202752) {               // w_dcn -> [oc][tap*64+c]
      int j = i - 165888;
      int oc = j / 576; int r = j - oc * 576; int tap = r >> 6; int c = r & 63;
      wFd[j] = (_Float16)w_dcn[(oc * 64 + c) * 9 + tap];
    }
    return;
  }
  if (bid < 1050) {
    int i = (bid - 792) * 256 + tid;       // 66048 = 4 buf * 4 b * 516 px * 8 chunks
    int bufi = i / 16512;
    int j = i - bufi * 16512;
    int b = j / 4128;
    int r = j - b * 4128;
    int p = r >> 3; int cg = r & 7;
    int row, col;
    if (p < 130)      { row = 0;   col = p; }
    else if (p < 260) { row = 129; col = p - 130; }
    else if (p < 388) { row = 1 + (p - 260); col = 0; }
    else              { row = 1 + (p - 388); col = 129; }
    _Float16* dst = (bufi == 0) ? X1 : (bufi == 1) ? X2 : (bufi == 2) ? B64 : C64;
    uint4 z; z.x = z.y = z.z = z.w = 0u;
    *(uint4*)(dst + ((size_t)(b * 130 + row) * 130 + col) * 64 + cg * 8) = z;
    return;
  }
  // ---- input prep: fp32 NCHW -> padded NHWC f16 (64-px half-rows)
  int j = bid - 1050;                      // 2048 = 2 src * 4 b * 128 y * 2 half
  int half = j & 1;
  int y = (j >> 1) & 127;
  int b = (j >> 8) & 3;
  int src = j >> 10;
  const float* sp = src ? refp : nbr;
  _Float16* dst = src ? X2 : X1;
  for (int l = tid; l < 64 * 64; l += 256) {
    int c = l >> 6, gx = l & 63;
    t[c * 65 + gx] = sp[(((size_t)b * 64 + c) << 14) + (y << 7) + half * 64 + gx];
  }
  __syncthreads();
  unsigned* dstU = (unsigned*)dst;
  for (int l = tid; l < 64 * 32; l += 256) {
    int pxl = l >> 5, c2 = l & 31;
    union { _Float16 h[2]; unsigned u; } pk;
    pk.h[0] = (_Float16)t[(2 * c2) * 65 + pxl];
    pk.h[1] = (_Float16)t[(2 * c2 + 1) * 65 + pxl];
    dstU[((size_t)(b * 130 + y + 1) * 130 + 1 + half * 64 + pxl) * 32 + c2] = pk.u;
  }
}

// ================ f16 MFMA conv3x3 (round-8 proven): 512 blocks, 4 waves, M=64 x N=32.
template <int NCH, bool SPLIT>
__global__ __launch_bounds__(256, 2) void conv3x3_f16_kernel(
    const _Float16* __restrict__ X1, const _Float16* __restrict__ X2,
    const _Float16* __restrict__ W, const float* __restrict__ bias,
    _Float16* __restrict__ outP) {
  int tid = threadIdx.x;
  int wv = tid >> 6, L = tid & 63;
  int lm = L & 15, lq = L >> 4;
  int bid = blockIdx.x;                 // 512 = 8 xcd * 16 ystrip * 4 b
  int xcd = bid & 7, j = bid >> 3;
  int y = (xcd << 4) | (j & 15);
  int b = j >> 4;
  int px0 = wv * 32;

  f4 acc[4][2];
#pragma unroll
  for (int i = 0; i < 4; ++i)
#pragma unroll
    for (int n = 0; n < 2; ++n) acc[i][n] = (f4)0.f;

#pragma unroll
  for (int c = 0; c < NCH; ++c) {
    const _Float16* src = (SPLIT && c >= 2) ? X2 : X1;
    int cl = SPLIT ? (c & 1) : c;
#pragma unroll
    for (int tap = 0; tap < 9; ++tap) {
      const int dy = tap / 3 - 1, dx = tap % 3 - 1;
      const _Float16* xb = src + ((size_t)((b * 130 + (y + 1 + dy)) * 130) + (1 + dx) + px0) * 64
                               + cl * 32 + lq * 8;
      h8 b0 = *(const h8*)(xb + lm * 64);
      h8 b1 = *(const h8*)(xb + (16 + lm) * 64);
      const _Float16* wp = W + (size_t)((tap * NCH + c) * 64) * 32 + lm * 32 + lq * 8;
      h8 a0 = *(const h8*)(wp);
      h8 a1 = *(const h8*)(wp + 512);
      h8 a2 = *(const h8*)(wp + 1024);
      h8 a3 = *(const h8*)(wp + 1536);
      acc[0][0] = __builtin_amdgcn_mfma_f32_16x16x32_f16(a0, b0, acc[0][0], 0, 0, 0);
      acc[1][0] = __builtin_amdgcn_mfma_f32_16x16x32_f16(a1, b0, acc[1][0], 0, 0, 0);
      acc[2][0] = __builtin_amdgcn_mfma_f32_16x16x32_f16(a2, b0, acc[2][0], 0, 0, 0);
      acc[3][0] = __builtin_amdgcn_mfma_f32_16x16x32_f16(a3, b0, acc[3][0], 0, 0, 0);
      acc[0][1] = __builtin_amdgcn_mfma_f32_16x16x32_f16(a0, b1, acc[0][1], 0, 0, 0);
      acc[1][1] = __builtin_amdgcn_mfma_f32_16x16x32_f16(a1, b1, acc[1][1], 0, 0, 0);
      acc[2][1] = __builtin_amdgcn_mfma_f32_16x16x32_f16(a2, b1, acc[2][1], 0, 0, 0);
      acc[3][1] = __builtin_amdgcn_mfma_f32_16x16x32_f16(a3, b1, acc[3][1], 0, 0, 0);
    }
  }
  const size_t obase = ((size_t)(b * 130 + (y + 1)) * 130 + 1) * 64;
#pragma unroll
  for (int mt = 0; mt < 4; ++mt)
#pragma unroll
    for (int nt = 0; nt < 2; ++nt) {
      int px = px0 + nt * 16 + lm;
      h4 pk;
#pragma unroll
      for (int r = 0; r < 4; ++r) {
        int oc = mt * 16 + lq * 4 + r;
        float v = acc[mt][nt][r] + bias[oc];
        v = (v >= 0.f) ? v : 0.1f * v;
        pk[r] = (_Float16)v;
      }
      *(h4*)(outP + obase + (size_t)px * 64 + mt * 16 + lq * 4) = pk;
    }
}

// ================ EXPERIMENT (conv2 only): wave tile M=64 x N=64, 2 waves/block,
// 512 blocks x 128 thr (4 waves/CU). Halves a-load instrs + addr work per FLOP;
// relies on ILP with the full 512-VGPR budget (launch_bounds(128,1)).
template <int NCH>
__global__ __launch_bounds__(128, 1) void conv3x3_w64_kernel(
    const _Float16* __restrict__ X1, const _Float16* __restrict__ W,
    const float* __restrict__ bias, _Float16* __restrict__ outP) {
  int tid = threadIdx.x;
  int wv = tid >> 6, L = tid & 63;
  int lm = L & 15, lq = L >> 4;
  int bid = blockIdx.x;                 // 512 = 8 xcd * 16 ystrip * 4 b
  int xcd = bid & 7, j = bid >> 3;
  int y = (xcd << 4) | (j & 15);
  int b = j >> 4;
  int px0 = wv * 64;

  f4 acc[4][4];
#pragma unroll
  for (int i = 0; i < 4; ++i)
#pragma unroll
    for (int n = 0; n < 4; ++n) acc[i][n] = (f4)0.f;

#pragma unroll
  for (int c = 0; c < NCH; ++c) {
#pragma unroll
    for (int tap = 0; tap < 9; ++tap) {
      const int dy = tap / 3 - 1, dx = tap % 3 - 1;
      const _Float16* xb = X1 + ((size_t)((b * 130 + (y + 1 + dy)) * 130) + (1 + dx) + px0) * 64
                              + c * 32 + lq * 8;
      h8 b0 = *(const h8*)(xb + lm * 64);
      h8 b1 = *(const h8*)(xb + (16 + lm) * 64);
      h8 b2 = *(const h8*)(xb + (32 + lm) * 64);
      h8 b3 = *(const h8*)(xb + (48 + lm) * 64);
      const _Float16* wp = W + (size_t)((tap * NCH + c) * 64) * 32 + lm * 32 + lq * 8;
      h8 a0 = *(const h8*)(wp);
      h8 a1 = *(const h8*)(wp + 512);
      h8 a2 = *(const h8*)(wp + 1024);
      h8 a3 = *(const h8*)(wp + 1536);
#pragma unroll
      for (int mt = 0; mt < 4; ++mt) {
        h8 am = (mt == 0) ? a0 : (mt == 1) ? a1 : (mt == 2) ? a2 : a3;
        acc[mt][0] = __builtin_amdgcn_mfma_f32_16x16x32_f16(am, b0, acc[mt][0], 0, 0, 0);
        acc[mt][1] = __builtin_amdgcn_mfma_f32_16x16x32_f16(am, b1, acc[mt][1], 0, 0, 0);
        acc[mt][2] = __builtin_amdgcn_mfma_f32_16x16x32_f16(am, b2, acc[mt][2], 0, 0, 0);
        acc[mt][3] = __builtin_amdgcn_mfma_f32_16x16x32_f16(am, b3, acc[mt][3], 0, 0, 0);
      }
    }
  }
  const size_t obase = ((size_t)(b * 130 + (y + 1)) * 130 + 1) * 64;
#pragma unroll
  for (int mt = 0; mt < 4; ++mt)
#pragma unroll
    for (int nt = 0; nt < 4; ++nt) {
      int px = px0 + nt * 16 + lm;
      h4 pk;
#pragma unroll
      for (int r = 0; r < 4; ++r) {
        int oc = mt * 16 + lq * 4 + r;
        float v = acc[mt][nt][r] + bias[oc];
        v = (v >= 0.f) ? v : 0.1f * v;
        pk[r] = (_Float16)v;
      }
      *(h4*)(outP + obase + (size_t)px * 64 + mt * 16 + lq * 4) = pk;
    }
}

// ================ FUSED conv_off + DCN, now with XCD y-strip swizzle for L2 locality.
// Block = 32 px (quarter row), 128 thr (2 waves). LDS S[32][328] + Soff[32][28].
__global__ __launch_bounds__(128, 4) void off_dcn_kernel(
    const _Float16* __restrict__ Xc, const _Float16* __restrict__ Xs,
    const _Float16* __restrict__ Wo, const float* __restrict__ bo,
    const _Float16* __restrict__ wD, const float* __restrict__ bd,
    float* __restrict__ off_out, float* __restrict__ mask_out,
    float* __restrict__ out) {
  __shared__ _Float16 S[32 * 328];
  __shared__ float Soff[32][28];        // per px: [0..17] offsets, [18..26] mask
  int tid = threadIdx.x;
  int wv = tid >> 6, L = tid & 63;
  int lm = L & 15, lq = L >> 4;
  int t8 = L >> 3, c8 = L & 7;
  int g = blockIdx.x;                   // 2048 = 8 xcd * (4 q * 16 ystrip * 4 b)
  int xcd = g & 7;
  int r0 = g >> 3;
  int q = r0 & 3;
  int y = (xcd << 4) | ((r0 >> 2) & 15);
  int b = r0 >> 6;
  int pxq0 = q * 32;

  // ---- phase 1: conv_off for 32 px; wave wv covers px pxq0+wv*16 .. +15
  {
    int px0 = pxq0 + wv * 16;
    f4 oa[2];
    oa[0] = (f4)0.f; oa[1] = (f4)0.f;
#pragma unroll
    for (int c = 0; c < 2; ++c)
#pragma unroll
      for (int tap = 0; tap < 9; ++tap) {
        const int dy = tap / 3 - 1, dx = tap % 3 - 1;
        const _Float16* xb = Xc + ((size_t)((b * 130 + (y + 1 + dy)) * 130) + (1 + dx) + px0) * 64
                                + c * 32 + lq * 8;
        h8 b0 = *(const h8*)(xb + lm * 64);
        const _Float16* wp = Wo + (size_t)((tap * 2 + c) * 32 + lm) * 32 + lq * 8;
        h8 a0 = *(const h8*)(wp);
        h8 a1 = *(const h8*)(wp + 512);
        oa[0] = __builtin_amdgcn_mfma_f32_16x16x32_f16(a0, b0, oa[0], 0, 0, 0);
        oa[1] = __builtin_amdgcn_mfma_f32_16x16x32_f16(a1, b0, oa[1], 0, 0, 0);
      }
    int gpx = px0 + lm;
    int hw = (y << 7) + gpx;
    int lpx = wv * 16 + lm;
#pragma unroll
    for (int mt = 0; mt < 2; ++mt)
#pragma unroll
      for (int r = 0; r < 4; ++r) {
        int oc = mt * 16 + lq * 4 + r;
        if (oc < 18) {
          float v = 15.f * tanhf(oa[mt][r] + bo[oc]);
          off_out[((b * 18 + oc) << 14) + hw] = v;
          Soff[lpx][oc] = v;
        } else if (oc < 27) {
          float v = 1.f / (1.f + expf(-(oa[mt][r] + bo[oc])));
          mask_out[((b * 9 + (oc - 18)) << 14) + hw] = v;
          Soff[lpx][oc] = v;
        }
      }
  }

  // ---- phase 2: DCN
  f4 acc[4];
#pragma unroll
  for (int i = 0; i < 4; ++i) acc[i] = (f4)0.f;

  for (int p = 0; p < 2; ++p) {
    const int tap0 = p ? 5 : 0;
    const int TAPS = p ? 4 : 5;
    __syncthreads();                     // covers Soff (p=0) and S reuse (p=1)
    const int NT = TAPS * 32;
    for (int u = wv * 8 + t8; u < NT; u += 16) {
      int px = u & 31;
      int tl = u >> 5;
      int k = tap0 + tl;
      int wg = pxq0 + px;
      int kr = k / 3;
      float oy = Soff[px][2 * k];
      float ox = Soff[px][2 * k + 1];
      float m = Soff[px][18 + k];
      float py = (float)(y + kr - 1) + oy;
      float pxf = (float)(wg + (k - kr * 3) - 1) + ox;
      float fy = floorf(py), fx = floorf(pxf);
      float wy = py - fy, wx = pxf - fx;
      int y0 = (int)fy, x0 = (int)fx;
      int y1 = y0 + 1, x1 = x0 + 1;
      float vy0 = ((unsigned)y0 < 128u) ? 1.f : 0.f;
      float vy1 = ((unsigned)y1 < 128u) ? 1.f : 0.f;
      float vx0 = ((unsigned)x0 < 128u) ? 1.f : 0.f;
      float vx1 = ((unsigned)x1 < 128u) ? 1.f : 0.f;
      float ey = 1.f - wy, ex = 1.f - wx;
      _Float16 w00 = (_Float16)(ey * ex * m * vy0 * vx0);
      _Float16 w01 = (_Float16)(ey * wx * m * vy0 * vx1);
      _Float16 w10 = (_Float16)(wy * ex * m * vy1 * vx0);
      _Float16 w11 = (_Float16)(wy * wx * m * vy1 * vx1);
      h2 W00 = {w00, w00}, W01 = {w01, w01}, W10 = {w10, w10}, W11 = {w11, w11};
      int y0c = min(max(y0, 0), 127) + 1, y1c = min(max(y1, 0), 127) + 1;
      int x0c = min(max(x0, 0), 127) + 1, x1c = min(max(x1, 0), 127) + 1;
      int rb = b * 130;
      h8 v00 = *(const h8*)(Xs + ((size_t)((rb + y0c) * 130 + x0c) << 6) + c8 * 8);
      h8 v01 = *(const h8*)(Xs + ((size_t)((rb + y0c) * 130 + x1c) << 6) + c8 * 8);
      h8 v10 = *(const h8*)(Xs + ((size_t)((rb + y1c) * 130 + x0c) << 6) + c8 * 8);
      h8 v11 = *(const h8*)(Xs + ((size_t)((rb + y1c) * 130 + x1c) << 6) + c8 * 8);
      h8 o;
#pragma unroll
      for (int j2 = 0; j2 < 4; ++j2) {
        h2 a = {v00[2 * j2], v00[2 * j2 + 1]};
        h2 bb = {v01[2 * j2], v01[2 * j2 + 1]};
        h2 cc = {v10[2 * j2], v10[2 * j2 + 1]};
        h2 dd = {v11[2 * j2], v11[2 * j2 + 1]};
        h2 r = a * W00;
        r += bb * W01;
        r += cc * W10;
        r += dd * W11;
        o[2 * j2] = r[0];
        o[2 * j2 + 1] = r[1];
      }
      *(h8*)&S[px * 328 + tl * 64 + c8 * 8] = o;
    }
    __syncthreads();
    const int KS = 2 * TAPS;
    for (int ks = 0; ks < KS; ++ks) {
      int kg = tap0 * 64 + ks * 32;
      const _Float16* wp = wD + (size_t)lm * 576 + kg + lq * 8;
      h8 a0 = *(const h8*)(wp);
      h8 a1 = *(const h8*)(wp + 16 * 576);
      h8 a2 = *(const h8*)(wp + 32 * 576);
      h8 a3 = *(const h8*)(wp + 48 * 576);
      h8 bv = *(const h8*)(&S[(wv * 16 + lm) * 328 + ks * 32 + lq * 8]);
      acc[0] = __builtin_amdgcn_mfma_f32_16x16x32_f16(a0, bv, acc[0], 0, 0, 0);
      acc[1] = __builtin_amdgcn_mfma_f32_16x16x32_f16(a1, bv, acc[1], 0, 0, 0);
      acc[2] = __builtin_amdgcn_mfma_f32_16x16x32_f16(a2, bv, acc[2], 0, 0, 0);
      acc[3] = __builtin_amdgcn_mfma_f32_16x16x32_f16(a3, bv, acc[3], 0, 0, 0);
    }
  }
  // epilogue: bias + lrelu, fp32 NCHW
  int px = pxq0 + wv * 16 + lm;
#pragma unroll
  for (int mt = 0; mt < 4; ++mt)
#pragma unroll
    for (int r = 0; r < 4; ++r) {
      int oc = mt * 16 + lq * 4 + r;
      float v = acc[mt][r] + bd[oc];
      v = (v >= 0.f) ? v : 0.1f * v;
      out[(((b << 6) + oc) << 14) + (y << 7) + px] = v;
    }
}

extern "C" void kernel_launch(void* const* d_in, const int* in_sizes, int n_in,
                              void* d_out, int out_size, void* d_ws, size_t ws_size,
                              hipStream_t stream) {
  const float* nbr   = (const float*)d_in[0];
  const float* refp  = (const float*)d_in[1];
  const float* w1    = (const float*)d_in[2];
  const float* b1    = (const float*)d_in[3];
  const float* w2    = (const float*)d_in[4];
  const float* b2    = (const float*)d_in[5];
  const float* w3    = (const float*)d_in[6];
  const float* b3    = (const float*)d_in[7];
  const float* w_off = (const float*)d_in[8];
  const float* b_off = (const float*)d_in[9];
  const float* w_dcn = (const float*)d_in[10];
  const float* b_dcn = (const float*)d_in[11];

  float* outp = (float*)d_out;
  float* feat = outp;                       // 4*64*16384
  float* offp = outp + 4194304;             // 4*18*16384
  float* mskp = outp + 4194304 + 1179648;   // 4*9*16384

  // ws layout: four padded NHWC f16 buffers [4][130][130][64] + f16 weights (~33.4 MiB)
  char* ws = (char*)d_ws;
  const size_t PB = 8652800;                // bytes per padded buffer
  _Float16* X1  = (_Float16*)ws;            // nbr padded (conv1 in + DCN sample src)
  _Float16* X2  = (_Float16*)(ws + PB);     // ref padded
  _Float16* B64 = (_Float16*)(ws + 2 * PB); // conv1 out / conv3 out
  _Float16* C64 = (_Float16*)(ws + 3 * PB); // conv2 out
  char* p = ws + 4 * PB;
  _Float16* wF1 = (_Float16*)p;  p += (size_t)73728 * 2;
  _Float16* wF2 = (_Float16*)p;  p += (size_t)36864 * 2;
  _Float16* wF3 = (_Float16*)p;  p += (size_t)36864 * 2;
  _Float16* wFo = (_Float16*)p;  p += (size_t)18432 * 2;
  _Float16* wFd = (_Float16*)p;

  // 5 dispatches total
  setup_kernel<<<dim3(3098), 256, 0, stream>>>(nbr, refp, w1, w2, w3, w_off, w_dcn,
                                               X1, X2, B64, C64, wF1, wF2, wF3, wFo, wFd);
  conv3x3_f16_kernel<4, true><<<dim3(512), 256, 0, stream>>>(X1, X2, wF1, b1, B64);
  // conv2: EXPERIMENT wave-tile M=64 x N=64 (conv3 stays as control twin)
  conv3x3_w64_kernel<2><<<dim3(512), 128, 0, stream>>>(B64, wF2, b2, C64);
  conv3x3_f16_kernel<2, false><<<dim3(512), 256, 0, stream>>>(C64, C64, wF3, b3, B64);
  off_dcn_kernel<<<dim3(2048), 128, 0, stream>>>(B64, X1, wFo, b_off, wFd, b_dcn,
                                                 offp, mskp, feat);
}

// Round 13
// 248.701 us; speedup vs baseline: 1.1533x; 1.0188x over previous
//
#include <hip/hip_runtime.h>
#include <math.h>

// Problem constants: B=4, NF=64, H=W=128, K=9
// d_in order: nbr, ref, w1, b1, w2, b2, w3, b3, w_off, b_off, w_dcn, b_dcn
// d_out: feat [4,64,128,128] | offset [4,18,128,128] | mask [4,9,128,128]

typedef _Float16 h8 __attribute__((ext_vector_type(8)));  // 8 f16 (4 VGPRs)
typedef _Float16 h4 __attribute__((ext_vector_type(4)));  // 4 f16 (2 VGPRs)
typedef _Float16 h2 __attribute__((ext_vector_type(2)));  // packed f16 pair
typedef float f4 __attribute__((ext_vector_type(4)));     // 4 fp32 acc

// ================ merged setup: weight prep + border zero + input prep ================
__global__ __launch_bounds__(256) void setup_kernel(
    const float* __restrict__ nbr, const float* __restrict__ refp,
    const float* __restrict__ w1, const float* __restrict__ w2,
    const float* __restrict__ w3, const float* __restrict__ w_off,
    const float* __restrict__ w_dcn,
    _Float16* __restrict__ X1, _Float16* __restrict__ X2,
    _Float16* __restrict__ B64, _Float16* __restrict__ C64,
    _Float16* __restrict__ wF1, _Float16* __restrict__ wF2,
    _Float16* __restrict__ wF3, _Float16* __restrict__ wFo,
    _Float16* __restrict__ wFd) {
  __shared__ float t[64 * 65];
  int bid = blockIdx.x;
  int tid = threadIdx.x;
  if (bid < 792) {
    int i = bid * 256 + tid;
    if (i < 73728) {                       // w1: NCH=4 (128 IC)
      int j = i;
      int icw = j & 31; int t1 = j >> 5; int oc = t1 & 63; int t2 = t1 >> 6;
      int ch = t2 & 3; int tap = t2 >> 2; int ic = ch * 32 + icw;
      wF1[j] = (_Float16)w1[(oc * 128 + ic) * 9 + tap];
    } else if (i < 110592) {               // w2
      int j = i - 73728;
      int icw = j & 31; int t1 = j >> 5; int oc = t1 & 63; int t2 = t1 >> 6;
      int ch = t2 & 1; int tap = t2 >> 1; int ic = ch * 32 + icw;
      wF2[j] = (_Float16)w2[(oc * 64 + ic) * 9 + tap];
    } else if (i < 147456) {               // w3
      int j = i - 110592;
      int icw = j & 31; int t1 = j >> 5; int oc = t1 & 63; int t2 = t1 >> 6;
      int ch = t2 & 1; int tap = t2 >> 1; int ic = ch * 32 + icw;
      wF3[j] = (_Float16)w3[(oc * 64 + ic) * 9 + tap];
    } else if (i < 165888) {               // w_off padded to 32 oc
      int j = i - 147456;
      int icw = j & 31; int t1 = j >> 5; int oc = t1 & 31; int t2 = t1 >> 5;
      int ch = t2 & 1; int tap = t2 >> 1; int ic = ch * 32 + icw;
      float v = (oc < 27) ? w_off[(oc * 64 + ic) * 9 + tap] : 0.f;
      wFo[j] = (_Float16)v;
    } else if (i < 202752) {               // w_dcn -> [oc][tap*64+c]
      int j = i - 165888;
      int oc = j / 576; int r = j - oc * 576; int tap = r >> 6; int c = r & 63;
      wFd[j] = (_Float16)w_dcn[(oc * 64 + c) * 9 + tap];
    }
    return;
  }
  if (bid < 1050) {
    int i = (bid - 792) * 256 + tid;       // 66048 = 4 buf * 4 b * 516 px * 8 chunks
    int bufi = i / 16512;
    int j = i - bufi * 16512;
    int b = j / 4128;
    int r = j - b * 4128;
    int p = r >> 3; int cg = r & 7;
    int row, col;
    if (p < 130)      { row = 0;   col = p; }
    else if (p < 260) { row = 129; col = p - 130; }
    else if (p < 388) { row = 1 + (p - 260); col = 0; }
    else              { row = 1 + (p - 388); col = 129; }
    _Float16* dst = (bufi == 0) ? X1 : (bufi == 1) ? X2 : (bufi == 2) ? B64 : C64;
    uint4 z; z.x = z.y = z.z = z.w = 0u;
    *(uint4*)(dst + ((size_t)(b * 130 + row) * 130 + col) * 64 + cg * 8) = z;
    return;
  }
  // ---- input prep: fp32 NCHW -> padded NHWC f16 (64-px half-rows)
  int j = bid - 1050;                      // 2048 = 2 src * 4 b * 128 y * 2 half
  int half = j & 1;
  int y = (j >> 1) & 127;
  int b = (j >> 8) & 3;
  int src = j >> 10;
  const float* sp = src ? refp : nbr;
  _Float16* dst = src ? X2 : X1;
  for (int l = tid; l < 64 * 64; l += 256) {
    int c = l >> 6, gx = l & 63;
    t[c * 65 + gx] = sp[(((size_t)b * 64 + c) << 14) + (y << 7) + half * 64 + gx];
  }
  __syncthreads();
  unsigned* dstU = (unsigned*)dst;
  for (int l = tid; l < 64 * 32; l += 256) {
    int pxl = l >> 5, c2 = l & 31;
    union { _Float16 h[2]; unsigned u; } pk;
    pk.h[0] = (_Float16)t[(2 * c2) * 65 + pxl];
    pk.h[1] = (_Float16)t[(2 * c2 + 1) * 65 + pxl];
    dstU[((size_t)(b * 130 + y + 1) * 130 + 1 + half * 64 + pxl) * 32 + c2] = pk.u;
  }
}

// ================ f16 MFMA conv3x3 (round-8 proven): 512 blocks, 4 waves, M=64 x N=32.
template <int NCH, bool SPLIT>
__global__ __launch_bounds__(256, 2) void conv3x3_f16_kernel(
    const _Float16* __restrict__ X1, const _Float16* __restrict__ X2,
    const _Float16* __restrict__ W, const float* __restrict__ bias,
    _Float16* __restrict__ outP) {
  int tid = threadIdx.x;
  int wv = tid >> 6, L = tid & 63;
  int lm = L & 15, lq = L >> 4;
  int bid = blockIdx.x;                 // 512 = 8 xcd * 16 ystrip * 4 b
  int xcd = bid & 7, j = bid >> 3;
  int y = (xcd << 4) | (j & 15);
  int b = j >> 4;
  int px0 = wv * 32;

  f4 acc[4][2];
#pragma unroll
  for (int i = 0; i < 4; ++i)
#pragma unroll
    for (int n = 0; n < 2; ++n) acc[i][n] = (f4)0.f;

#pragma unroll
  for (int c = 0; c < NCH; ++c) {
    const _Float16* src = (SPLIT && c >= 2) ? X2 : X1;
    int cl = SPLIT ? (c & 1) : c;
#pragma unroll
    for (int tap = 0; tap < 9; ++tap) {
      const int dy = tap / 3 - 1, dx = tap % 3 - 1;
      const _Float16* xb = src + ((size_t)((b * 130 + (y + 1 + dy)) * 130) + (1 + dx) + px0) * 64
                               + cl * 32 + lq * 8;
      h8 b0 = *(const h8*)(xb + lm * 64);
      h8 b1 = *(const h8*)(xb + (16 + lm) * 64);
      const _Float16* wp = W + (size_t)((tap * NCH + c) * 64) * 32 + lm * 32 + lq * 8;
      h8 a0 = *(const h8*)(wp);
      h8 a1 = *(const h8*)(wp + 512);
      h8 a2 = *(const h8*)(wp + 1024);
      h8 a3 = *(const h8*)(wp + 1536);
      acc[0][0] = __builtin_amdgcn_mfma_f32_16x16x32_f16(a0, b0, acc[0][0], 0, 0, 0);
      acc[1][0] = __builtin_amdgcn_mfma_f32_16x16x32_f16(a1, b0, acc[1][0], 0, 0, 0);
      acc[2][0] = __builtin_amdgcn_mfma_f32_16x16x32_f16(a2, b0, acc[2][0], 0, 0, 0);
      acc[3][0] = __builtin_amdgcn_mfma_f32_16x16x32_f16(a3, b0, acc[3][0], 0, 0, 0);
      acc[0][1] = __builtin_amdgcn_mfma_f32_16x16x32_f16(a0, b1, acc[0][1], 0, 0, 0);
      acc[1][1] = __builtin_amdgcn_mfma_f32_16x16x32_f16(a1, b1, acc[1][1], 0, 0, 0);
      acc[2][1] = __builtin_amdgcn_mfma_f32_16x16x32_f16(a2, b1, acc[2][1], 0, 0, 0);
      acc[3][1] = __builtin_amdgcn_mfma_f32_16x16x32_f16(a3, b1, acc[3][1], 0, 0, 0);
    }
  }
  const size_t obase = ((size_t)(b * 130 + (y + 1)) * 130 + 1) * 64;
#pragma unroll
  for (int mt = 0; mt < 4; ++mt)
#pragma unroll
    for (int nt = 0; nt < 2; ++nt) {
      int px = px0 + nt * 16 + lm;
      h4 pk;
#pragma unroll
      for (int r = 0; r < 4; ++r) {
        int oc = mt * 16 + lq * 4 + r;
        float v = acc[mt][nt][r] + bias[oc];
        v = (v >= 0.f) ? v : 0.1f * v;
        pk[r] = (_Float16)v;
      }
      *(h4*)(outP + obase + (size_t)px * 64 + mt * 16 + lq * 4) = pk;
    }
}

// ================ w64 conv: wave tile M=64 x N=64, 2 waves/block, 512 blocks x 128 thr.
// Halves a-load instrs + addr work per FLOP; ILP with full VGPR budget (128,1).
template <int NCH>
__global__ __launch_bounds__(128, 1) void conv3x3_w64_kernel(
    const _Float16* __restrict__ X1, const _Float16* __restrict__ W,
    const float* __restrict__ bias, _Float16* __restrict__ outP) {
  int tid = threadIdx.x;
  int wv = tid >> 6, L = tid & 63;
  int lm = L & 15, lq = L >> 4;
  int bid = blockIdx.x;                 // 512 = 8 xcd * 16 ystrip * 4 b
  int xcd = bid & 7, j = bid >> 3;
  int y = (xcd << 4) | (j & 15);
  int b = j >> 4;
  int px0 = wv * 64;

  f4 acc[4][4];
#pragma unroll
  for (int i = 0; i < 4; ++i)
#pragma unroll
    for (int n = 0; n < 4; ++n) acc[i][n] = (f4)0.f;

#pragma unroll
  for (int c = 0; c < NCH; ++c) {
#pragma unroll
    for (int tap = 0; tap < 9; ++tap) {
      const int dy = tap / 3 - 1, dx = tap % 3 - 1;
      const _Float16* xb = X1 + ((size_t)((b * 130 + (y + 1 + dy)) * 130) + (1 + dx) + px0) * 64
                              + c * 32 + lq * 8;
      h8 b0 = *(const h8*)(xb + lm * 64);
      h8 b1 = *(const h8*)(xb + (16 + lm) * 64);
      h8 b2 = *(const h8*)(xb + (32 + lm) * 64);
      h8 b3 = *(const h8*)(xb + (48 + lm) * 64);
      const _Float16* wp = W + (size_t)((tap * NCH + c) * 64) * 32 + lm * 32 + lq * 8;
      h8 a0 = *(const h8*)(wp);
      h8 a1 = *(const h8*)(wp + 512);
      h8 a2 = *(const h8*)(wp + 1024);
      h8 a3 = *(const h8*)(wp + 1536);
#pragma unroll
      for (int mt = 0; mt < 4; ++mt) {
        h8 am = (mt == 0) ? a0 : (mt == 1) ? a1 : (mt == 2) ? a2 : a3;
        acc[mt][0] = __builtin_amdgcn_mfma_f32_16x16x32_f16(am, b0, acc[mt][0], 0, 0, 0);
        acc[mt][1] = __builtin_amdgcn_mfma_f32_16x16x32_f16(am, b1, acc[mt][1], 0, 0, 0);
        acc[mt][2] = __builtin_amdgcn_mfma_f32_16x16x32_f16(am, b2, acc[mt][2], 0, 0, 0);
        acc[mt][3] = __builtin_amdgcn_mfma_f32_16x16x32_f16(am, b3, acc[mt][3], 0, 0, 0);
      }
    }
  }
  const size_t obase = ((size_t)(b * 130 + (y + 1)) * 130 + 1) * 64;
#pragma unroll
  for (int mt = 0; mt < 4; ++mt)
#pragma unroll
    for (int nt = 0; nt < 4; ++nt) {
      int px = px0 + nt * 16 + lm;
      h4 pk;
#pragma unroll
      for (int r = 0; r < 4; ++r) {
        int oc = mt * 16 + lq * 4 + r;
        float v = acc[mt][nt][r] + bias[oc];
        v = (v >= 0.f) ? v : 0.1f * v;
        pk[r] = (_Float16)v;
      }
      *(h4*)(outP + obase + (size_t)px * 64 + mt * 16 + lq * 4) = pk;
    }
}

// ================ FUSED conv_off + DCN, XCD swizzle + fully-unrolled sampling for MLP.
// Block = 32 px (quarter row), 128 thr (2 waves). LDS S[32][328] + Soff[32][28].
// launch_bounds(128,3): 6 blocks/CU (LDS-limited 148/160 KB), VGPR cap 170.
__global__ __launch_bounds__(128, 3) void off_dcn_kernel(
    const _Float16* __restrict__ Xc, const _Float16* __restrict__ Xs,
    const _Float16* __restrict__ Wo, const float* __restrict__ bo,
    const _Float16* __restrict__ wD, const float* __restrict__ bd,
    float* __restrict__ off_out, float* __restrict__ mask_out,
    float* __restrict__ out) {
  __shared__ _Float16 S[32 * 328];
  __shared__ float Soff[32][28];        // per px: [0..17] offsets, [18..26] mask
  int tid = threadIdx.x;
  int wv = tid >> 6, L = tid & 63;
  int lm = L & 15, lq = L >> 4;
  int t8 = L >> 3, c8 = L & 7;
  int g = blockIdx.x;                   // 2048 = 8 xcd * (4 q * 16 ystrip * 4 b)
  int xcd = g & 7;
  int r0 = g >> 3;
  int q = r0 & 3;
  int y = (xcd << 4) | ((r0 >> 2) & 15);
  int b = r0 >> 6;
  int pxq0 = q * 32;

  // ---- phase 1: conv_off for 32 px; wave wv covers px pxq0+wv*16 .. +15
  {
    int px0 = pxq0 + wv * 16;
    f4 oa[2];
    oa[0] = (f4)0.f; oa[1] = (f4)0.f;
#pragma unroll
    for (int c = 0; c < 2; ++c)
#pragma unroll
      for (int tap = 0; tap < 9; ++tap) {
        const int dy = tap / 3 - 1, dx = tap % 3 - 1;
        const _Float16* xb = Xc + ((size_t)((b * 130 + (y + 1 + dy)) * 130) + (1 + dx) + px0) * 64
                                + c * 32 + lq * 8;
        h8 b0 = *(const h8*)(xb + lm * 64);
        const _Float16* wp = Wo + (size_t)((tap * 2 + c) * 32 + lm) * 32 + lq * 8;
        h8 a0 = *(const h8*)(wp);
        h8 a1 = *(const h8*)(wp + 512);
        oa[0] = __builtin_amdgcn_mfma_f32_16x16x32_f16(a0, b0, oa[0], 0, 0, 0);
        oa[1] = __builtin_amdgcn_mfma_f32_16x16x32_f16(a1, b0, oa[1], 0, 0, 0);
      }
    int gpx = px0 + lm;
    int hw = (y << 7) + gpx;
    int lpx = wv * 16 + lm;
#pragma unroll
    for (int mt = 0; mt < 2; ++mt)
#pragma unroll
      for (int r = 0; r < 4; ++r) {
        int oc = mt * 16 + lq * 4 + r;
        if (oc < 18) {
          float v = 15.f * tanhf(oa[mt][r] + bo[oc]);
          off_out[((b * 18 + oc) << 14) + hw] = v;
          Soff[lpx][oc] = v;
        } else if (oc < 27) {
          float v = 1.f / (1.f + expf(-(oa[mt][r] + bo[oc])));
          mask_out[((b * 9 + (oc - 18)) << 14) + hw] = v;
          Soff[lpx][oc] = v;
        }
      }
  }

  // ---- phase 2: DCN
  f4 acc[4];
#pragma unroll
  for (int i = 0; i < 4; ++i) acc[i] = (f4)0.f;

#pragma unroll
  for (int p = 0; p < 2; ++p) {
    const int tap0 = p ? 5 : 0;
    const int TAPS = p ? 4 : 5;
    __syncthreads();                     // covers Soff (p=0) and S reuse (p=1)
    // sampling: 8 lanes per (px, tap) task; compile-time trip count, fully unrolled
    // so all iterations' gathers issue together (MLP hides L2 latency).
#pragma unroll
    for (int it = 0; it < 2 * TAPS; ++it) {
      int u = it * 16 + wv * 8 + t8;
      int px = u & 31;
      int tl = u >> 5;
      int k = tap0 + tl;
      int wg = pxq0 + px;
      int kr = k / 3;
      float oy = Soff[px][2 * k];
      float ox = Soff[px][2 * k + 1];
      float m = Soff[px][18 + k];
      float py = (float)(y + kr - 1) + oy;
      float pxf = (float)(wg + (k - kr * 3) - 1) + ox;
      float fy = floorf(py), fx = floorf(pxf);
      float wy = py - fy, wx = pxf - fx;
      int y0 = (int)fy, x0 = (int)fx;
      int y1 = y0 + 1, x1 = x0 + 1;
      float vy0 = ((unsigned)y0 < 128u) ? 1.f : 0.f;
      float vy1 = ((unsigned)y1 < 128u) ? 1.f : 0.f;
      float vx0 = ((unsigned)x0 < 128u) ? 1.f : 0.f;
      float vx1 = ((unsigned)x1 < 128u) ? 1.f : 0.f;
      float ey = 1.f - wy, ex = 1.f - wx;
      _Float16 w00 = (_Float16)(ey * ex * m * vy0 * vx0);
      _Float16 w01 = (_Float16)(ey * wx * m * vy0 * vx1);
      _Float16 w10 = (_Float16)(wy * ex * m * vy1 * vx0);
      _Float16 w11 = (_Float16)(wy * wx * m * vy1 * vx1);
      h2 W00 = {w00, w00}, W01 = {w01, w01}, W10 = {w10, w10}, W11 = {w11, w11};
      int y0c = min(max(y0, 0), 127) + 1, y1c = min(max(y1, 0), 127) + 1;
      int x0c = min(max(x0, 0), 127) + 1, x1c = min(max(x1, 0), 127) + 1;
      int rb = b * 130;
      h8 v00 = *(const h8*)(Xs + ((size_t)((rb + y0c) * 130 + x0c) << 6) + c8 * 8);
      h8 v01 = *(const h8*)(Xs + ((size_t)((rb + y0c) * 130 + x1c) << 6) + c8 * 8);
      h8 v10 = *(const h8*)(Xs + ((size_t)((rb + y1c) * 130 + x0c) << 6) + c8 * 8);
      h8 v11 = *(const h8*)(Xs + ((size_t)((rb + y1c) * 130 + x1c) << 6) + c8 * 8);
      h8 o;
#pragma unroll
      for (int j2 = 0; j2 < 4; ++j2) {
        h2 a = {v00[2 * j2], v00[2 * j2 + 1]};
        h2 bb = {v01[2 * j2], v01[2 * j2 + 1]};
        h2 cc = {v10[2 * j2], v10[2 * j2 + 1]};
        h2 dd = {v11[2 * j2], v11[2 * j2 + 1]};
        h2 r = a * W00;
        r += bb * W01;
        r += cc * W10;
        r += dd * W11;
        o[2 * j2] = r[0];
        o[2 * j2 + 1] = r[1];
      }
      *(h8*)&S[px * 328 + tl * 64 + c8 * 8] = o;
    }
    __syncthreads();
    const int KS = 2 * TAPS;
#pragma unroll
    for (int ks = 0; ks < KS; ++ks) {
      int kg = tap0 * 64 + ks * 32;
      const _Float16* wp = wD + (size_t)lm * 576 + kg + lq * 8;
      h8 a0 = *(const h8*)(wp);
      h8 a1 = *(const h8*)(wp + 16 * 576);
      h8 a2 = *(const h8*)(wp + 32 * 576);
      h8 a3 = *(const h8*)(wp + 48 * 576);
      h8 bv = *(const h8*)(&S[(wv * 16 + lm) * 328 + ks * 32 + lq * 8]);
      acc[0] = __builtin_amdgcn_mfma_f32_16x16x32_f16(a0, bv, acc[0], 0, 0, 0);
      acc[1] = __builtin_amdgcn_mfma_f32_16x16x32_f16(a1, bv, acc[1], 0, 0, 0);
      acc[2] = __builtin_amdgcn_mfma_f32_16x16x32_f16(a2, bv, acc[2], 0, 0, 0);
      acc[3] = __builtin_amdgcn_mfma_f32_16x16x32_f16(a3, bv, acc[3], 0, 0, 0);
    }
  }
  // epilogue: bias + lrelu, fp32 NCHW
  int px = pxq0 + wv * 16 + lm;
#pragma unroll
  for (int mt = 0; mt < 4; ++mt)
#pragma unroll
    for (int r = 0; r < 4; ++r) {
      int oc = mt * 16 + lq * 4 + r;
      float v = acc[mt][r] + bd[oc];
      v = (v >= 0.f) ? v : 0.1f * v;
      out[(((b << 6) + oc) << 14) + (y << 7) + px] = v;
    }
}

extern "C" void kernel_launch(void* const* d_in, const int* in_sizes, int n_in,
                              void* d_out, int out_size, void* d_ws, size_t ws_size,
                              hipStream_t stream) {
  const float* nbr   = (const float*)d_in[0];
  const float* refp  = (const float*)d_in[1];
  const float* w1    = (const float*)d_in[2];
  const float* b1    = (const float*)d_in[3];
  const float* w2    = (const float*)d_in[4];
  const float* b2    = (const float*)d_in[5];
  const float* w3    = (const float*)d_in[6];
  const float* b3    = (const float*)d_in[7];
  const float* w_off = (const float*)d_in[8];
  const float* b_off = (const float*)d_in[9];
  const float* w_dcn = (const float*)d_in[10];
  const float* b_dcn = (const float*)d_in[11];

  float* outp = (float*)d_out;
  float* feat = outp;                       // 4*64*16384
  float* offp = outp + 4194304;             // 4*18*16384
  float* mskp = outp + 4194304 + 1179648;   // 4*9*16384

  // ws layout: four padded NHWC f16 buffers [4][130][130][64] + f16 weights (~33.4 MiB)
  char* ws = (char*)d_ws;
  const size_t PB = 8652800;                // bytes per padded buffer
  _Float16* X1  = (_Float16*)ws;            // nbr padded (conv1 in + DCN sample src)
  _Float16* X2  = (_Float16*)(ws + PB);     // ref padded
  _Float16* B64 = (_Float16*)(ws + 2 * PB); // conv1 out / conv3 out
  _Float16* C64 = (_Float16*)(ws + 3 * PB); // conv2 out
  char* p = ws + 4 * PB;
  _Float16* wF1 = (_Float16*)p;  p += (size_t)73728 * 2;
  _Float16* wF2 = (_Float16*)p;  p += (size_t)36864 * 2;
  _Float16* wF3 = (_Float16*)p;  p += (size_t)36864 * 2;
  _Float16* wFo = (_Float16*)p;  p += (size_t)18432 * 2;
  _Float16* wFd = (_Float16*)p;

  // 5 dispatches total
  setup_kernel<<<dim3(3098), 256, 0, stream>>>(nbr, refp, w1, w2, w3, w_off, w_dcn,
                                               X1, X2, B64, C64, wF1, wF2, wF3, wFo, wFd);
  conv3x3_f16_kernel<4, true><<<dim3(512), 256, 0, stream>>>(X1, X2, wF1, b1, B64);
  conv3x3_w64_kernel<2><<<dim3(512), 128, 0, stream>>>(B64, wF2, b2, C64);
  conv3x3_w64_kernel<2><<<dim3(512), 128, 0, stream>>>(C64, wF3, b3, B64);
  off_dcn_kernel<<<dim3(2048), 128, 0, stream>>>(B64, X1, wFo, b_off, wFd, b_dcn,
                                                 offp, mskp, feat);
}

// Round 14
// 228.518 us; speedup vs baseline: 1.2552x; 1.0883x over previous
//
#include <hip/hip_runtime.h>
#include <math.h>

// Problem constants: B=4, NF=64, H=W=128, K=9
// d_in order: nbr, ref, w1, b1, w2, b2, w3, b3, w_off, b_off, w_dcn, b_dcn
// d_out: feat [4,64,128,128] | offset [4,18,128,128] | mask [4,9,128,128]

typedef _Float16 h8 __attribute__((ext_vector_type(8)));  // 8 f16 (4 VGPRs)
typedef _Float16 h4 __attribute__((ext_vector_type(4)));  // 4 f16 (2 VGPRs)
typedef _Float16 h2 __attribute__((ext_vector_type(2)));  // packed f16 pair
typedef float f4 __attribute__((ext_vector_type(4)));     // 4 fp32 acc

// ================ merged setup: weight prep + border zero + input prep ================
__global__ __launch_bounds__(256) void setup_kernel(
    const float* __restrict__ nbr, const float* __restrict__ refp,
    const float* __restrict__ w1, const float* __restrict__ w2,
    const float* __restrict__ w3, const float* __restrict__ w_off,
    const float* __restrict__ w_dcn,
    _Float16* __restrict__ X1, _Float16* __restrict__ X2,
    _Float16* __restrict__ B64, _Float16* __restrict__ C64,
    _Float16* __restrict__ wF1, _Float16* __restrict__ wF2,
    _Float16* __restrict__ wF3, _Float16* __restrict__ wFo,
    _Float16* __restrict__ wFd) {
  __shared__ float t[64 * 65];
  int bid = blockIdx.x;
  int tid = threadIdx.x;
  if (bid < 792) {
    int i = bid * 256 + tid;
    if (i < 73728) {                       // w1: NCH=4 (128 IC)
      int j = i;
      int icw = j & 31; int t1 = j >> 5; int oc = t1 & 63; int t2 = t1 >> 6;
      int ch = t2 & 3; int tap = t2 >> 2; int ic = ch * 32 + icw;
      wF1[j] = (_Float16)w1[(oc * 128 + ic) * 9 + tap];
    } else if (i < 110592) {               // w2
      int j = i - 73728;
      int icw = j & 31; int t1 = j >> 5; int oc = t1 & 63; int t2 = t1 >> 6;
      int ch = t2 & 1; int tap = t2 >> 1; int ic = ch * 32 + icw;
      wF2[j] = (_Float16)w2[(oc * 64 + ic) * 9 + tap];
    } else if (i < 147456) {               // w3
      int j = i - 110592;
      int icw = j & 31; int t1 = j >> 5; int oc = t1 & 63; int t2 = t1 >> 6;
      int ch = t2 & 1; int tap = t2 >> 1; int ic = ch * 32 + icw;
      wF3[j] = (_Float16)w3[(oc * 64 + ic) * 9 + tap];
    } else if (i < 165888) {               // w_off padded to 32 oc
      int j = i - 147456;
      int icw = j & 31; int t1 = j >> 5; int oc = t1 & 31; int t2 = t1 >> 5;
      int ch = t2 & 1; int tap = t2 >> 1; int ic = ch * 32 + icw;
      float v = (oc < 27) ? w_off[(oc * 64 + ic) * 9 + tap] : 0.f;
      wFo[j] = (_Float16)v;
    } else if (i < 202752) {               // w_dcn -> [oc][tap*64+c]
      int j = i - 165888;
      int oc = j / 576; int r = j - oc * 576; int tap = r >> 6; int c = r & 63;
      wFd[j] = (_Float16)w_dcn[(oc * 64 + c) * 9 + tap];
    }
    return;
  }
  if (bid < 1050) {
    int i = (bid - 792) * 256 + tid;       // 66048 = 4 buf * 4 b * 516 px * 8 chunks
    int bufi = i / 16512;
    int j = i - bufi * 16512;
    int b = j / 4128;
    int r = j - b * 4128;
    int p = r >> 3; int cg = r & 7;
    int row, col;
    if (p < 130)      { row = 0;   col = p; }
    else if (p < 260) { row = 129; col = p - 130; }
    else if (p < 388) { row = 1 + (p - 260); col = 0; }
    else              { row = 1 + (p - 388); col = 129; }
    _Float16* dst = (bufi == 0) ? X1 : (bufi == 1) ? X2 : (bufi == 2) ? B64 : C64;
    uint4 z; z.x = z.y = z.z = z.w = 0u;
    *(uint4*)(dst + ((size_t)(b * 130 + row) * 130 + col) * 64 + cg * 8) = z;
    return;
  }
  // ---- input prep: fp32 NCHW -> padded NHWC f16 (64-px half-rows)
  int j = bid - 1050;                      // 2048 = 2 src * 4 b * 128 y * 2 half
  int half = j & 1;
  int y = (j >> 1) & 127;
  int b = (j >> 8) & 3;
  int src = j >> 10;
  const float* sp = src ? refp : nbr;
  _Float16* dst = src ? X2 : X1;
  for (int l = tid; l < 64 * 64; l += 256) {
    int c = l >> 6, gx = l & 63;
    t[c * 65 + gx] = sp[(((size_t)b * 64 + c) << 14) + (y << 7) + half * 64 + gx];
  }
  __syncthreads();
  unsigned* dstU = (unsigned*)dst;
  for (int l = tid; l < 64 * 32; l += 256) {
    int pxl = l >> 5, c2 = l & 31;
    union { _Float16 h[2]; unsigned u; } pk;
    pk.h[0] = (_Float16)t[(2 * c2) * 65 + pxl];
    pk.h[1] = (_Float16)t[(2 * c2 + 1) * 65 + pxl];
    dstU[((size_t)(b * 130 + y + 1) * 130 + 1 + half * 64 + pxl) * 32 + c2] = pk.u;
  }
}

// ================ w64 conv: wave tile M=64 x N=64, 2 waves/block, 512 blocks x 128 thr.
// Halves a-load instrs + addr work per FLOP; ILP with full VGPR budget (128,1).
// SPLIT: concat of X1 (c<2) and X2 (c>=2) for conv1.
template <int NCH, bool SPLIT>
__global__ __launch_bounds__(128, 1) void conv3x3_w64_kernel(
    const _Float16* __restrict__ X1, const _Float16* __restrict__ X2,
    const _Float16* __restrict__ W, const float* __restrict__ bias,
    _Float16* __restrict__ outP) {
  int tid = threadIdx.x;
  int wv = tid >> 6, L = tid & 63;
  int lm = L & 15, lq = L >> 4;
  int bid = blockIdx.x;                 // 512 = 8 xcd * 16 ystrip * 4 b
  int xcd = bid & 7, j = bid >> 3;
  int y = (xcd << 4) | (j & 15);
  int b = j >> 4;
  int px0 = wv * 64;

  f4 acc[4][4];
#pragma unroll
  for (int i = 0; i < 4; ++i)
#pragma unroll
    for (int n = 0; n < 4; ++n) acc[i][n] = (f4)0.f;

#pragma unroll
  for (int c = 0; c < NCH; ++c) {
    const _Float16* src = (SPLIT && c >= 2) ? X2 : X1;
    int cl = SPLIT ? (c & 1) : c;
#pragma unroll
    for (int tap = 0; tap < 9; ++tap) {
      const int dy = tap / 3 - 1, dx = tap % 3 - 1;
      const _Float16* xb = src + ((size_t)((b * 130 + (y + 1 + dy)) * 130) + (1 + dx) + px0) * 64
                               + cl * 32 + lq * 8;
      h8 b0 = *(const h8*)(xb + lm * 64);
      h8 b1 = *(const h8*)(xb + (16 + lm) * 64);
      h8 b2 = *(const h8*)(xb + (32 + lm) * 64);
      h8 b3 = *(const h8*)(xb + (48 + lm) * 64);
      const _Float16* wp = W + (size_t)((tap * NCH + c) * 64) * 32 + lm * 32 + lq * 8;
      h8 a0 = *(const h8*)(wp);
      h8 a1 = *(const h8*)(wp + 512);
      h8 a2 = *(const h8*)(wp + 1024);
      h8 a3 = *(const h8*)(wp + 1536);
#pragma unroll
      for (int mt = 0; mt < 4; ++mt) {
        h8 am = (mt == 0) ? a0 : (mt == 1) ? a1 : (mt == 2) ? a2 : a3;
        acc[mt][0] = __builtin_amdgcn_mfma_f32_16x16x32_f16(am, b0, acc[mt][0], 0, 0, 0);
        acc[mt][1] = __builtin_amdgcn_mfma_f32_16x16x32_f16(am, b1, acc[mt][1], 0, 0, 0);
        acc[mt][2] = __builtin_amdgcn_mfma_f32_16x16x32_f16(am, b2, acc[mt][2], 0, 0, 0);
        acc[mt][3] = __builtin_amdgcn_mfma_f32_16x16x32_f16(am, b3, acc[mt][3], 0, 0, 0);
      }
    }
  }
  const size_t obase = ((size_t)(b * 130 + (y + 1)) * 130 + 1) * 64;
#pragma unroll
  for (int mt = 0; mt < 4; ++mt)
#pragma unroll
    for (int nt = 0; nt < 4; ++nt) {
      int px = px0 + nt * 16 + lm;
      h4 pk;
#pragma unroll
      for (int r = 0; r < 4; ++r) {
        int oc = mt * 16 + lq * 4 + r;
        float v = acc[mt][nt][r] + bias[oc];
        v = (v >= 0.f) ? v : 0.1f * v;
        pk[r] = (_Float16)v;
      }
      *(h4*)(outP + obase + (size_t)px * 64 + mt * 16 + lq * 4) = pk;
    }
}

// ================ FUSED conv_off + DCN: 4 waves per 32-px block for 2x TLP.
// Block = 32 px (quarter row), 256 thr (4 waves). LDS S[32][328] + Soff[32][28].
// Phase 1 (conv_off): waves 0-1 only (M=32 x N=16 each). Phase 2: sampling split
// 4 ways (8 lanes/task, 32 tasks/iter); MFMA D[64oc][32px] split into quadrants
// (wave = Mhalf x Nhalf, acc 2 tiles). launch_bounds(256,6): 6 blocks/CU by LDS.
__global__ __launch_bounds__(256, 6) void off_dcn_kernel(
    const _Float16* __restrict__ Xc, const _Float16* __restrict__ Xs,
    const _Float16* __restrict__ Wo, const float* __restrict__ bo,
    const _Float16* __restrict__ wD, const float* __restrict__ bd,
    float* __restrict__ off_out, float* __restrict__ mask_out,
    float* __restrict__ out) {
  __shared__ _Float16 S[32 * 328];
  __shared__ float Soff[32][28];        // per px: [0..17] offsets, [18..26] mask
  int tid = threadIdx.x;
  int wv = tid >> 6, L = tid & 63;
  int lm = L & 15, lq = L >> 4;
  int t8 = L >> 3, c8 = L & 7;
  int g = blockIdx.x;                   // 2048 = 8 xcd * (4 q * 16 ystrip * 4 b)
  int xcd = g & 7;
  int r0 = g >> 3;
  int q = r0 & 3;
  int y = (xcd << 4) | ((r0 >> 2) & 15);
  int b = r0 >> 6;
  int pxq0 = q * 32;

  // ---- phase 1: conv_off for 32 px on waves 0-1 (wave wv covers px half wv)
  if (wv < 2) {
    int px0 = pxq0 + wv * 16;
    f4 oa[2];
    oa[0] = (f4)0.f; oa[1] = (f4)0.f;
#pragma unroll
    for (int c = 0; c < 2; ++c)
#pragma unroll
      for (int tap = 0; tap < 9; ++tap) {
        const int dy = tap / 3 - 1, dx = tap % 3 - 1;
        const _Float16* xb = Xc + ((size_t)((b * 130 + (y + 1 + dy)) * 130) + (1 + dx) + px0) * 64
                                + c * 32 + lq * 8;
        h8 b0 = *(const h8*)(xb + lm * 64);
        const _Float16* wp = Wo + (size_t)((tap * 2 + c) * 32 + lm) * 32 + lq * 8;
        h8 a0 = *(const h8*)(wp);
        h8 a1 = *(const h8*)(wp + 512);
        oa[0] = __builtin_amdgcn_mfma_f32_16x16x32_f16(a0, b0, oa[0], 0, 0, 0);
        oa[1] = __builtin_amdgcn_mfma_f32_16x16x32_f16(a1, b0, oa[1], 0, 0, 0);
      }
    int gpx = px0 + lm;
    int hw = (y << 7) + gpx;
    int lpx = wv * 16 + lm;
#pragma unroll
    for (int mt = 0; mt < 2; ++mt)
#pragma unroll
      for (int r = 0; r < 4; ++r) {
        int oc = mt * 16 + lq * 4 + r;
        if (oc < 18) {
          float v = 15.f * tanhf(oa[mt][r] + bo[oc]);
          off_out[((b * 18 + oc) << 14) + hw] = v;
          Soff[lpx][oc] = v;
        } else if (oc < 27) {
          float v = 1.f / (1.f + expf(-(oa[mt][r] + bo[oc])));
          mask_out[((b * 9 + (oc - 18)) << 14) + hw] = v;
          Soff[lpx][oc] = v;
        }
      }
  }

  // ---- phase 2: DCN
  f4 acc[2];
  acc[0] = (f4)0.f; acc[1] = (f4)0.f;
  int wvM = wv >> 1, wvN = wv & 1;      // MFMA quadrant for this wave

#pragma unroll
  for (int p = 0; p < 2; ++p) {
    const int tap0 = p ? 5 : 0;
    const int TAPS = p ? 4 : 5;
    __syncthreads();                     // covers Soff (p=0) and S reuse (p=1)
    // sampling: 8 lanes per (px, tap) task; 32 tasks per block-iteration (4 waves)
#pragma unroll
    for (int it = 0; it < TAPS; ++it) {
      int u = it * 32 + wv * 8 + t8;
      int px = u & 31;
      int tl = u >> 5;
      int k = tap0 + tl;
      int wg = pxq0 + px;
      int kr = k / 3;
      float oy = Soff[px][2 * k];
      float ox = Soff[px][2 * k + 1];
      float m = Soff[px][18 + k];
      float py = (float)(y + kr - 1) + oy;
      float pxf = (float)(wg + (k - kr * 3) - 1) + ox;
      float fy = floorf(py), fx = floorf(pxf);
      float wy = py - fy, wx = pxf - fx;
      int y0 = (int)fy, x0 = (int)fx;
      int y1 = y0 + 1, x1 = x0 + 1;
      float vy0 = ((unsigned)y0 < 128u) ? 1.f : 0.f;
      float vy1 = ((unsigned)y1 < 128u) ? 1.f : 0.f;
      float vx0 = ((unsigned)x0 < 128u) ? 1.f : 0.f;
      float vx1 = ((unsigned)x1 < 128u) ? 1.f : 0.f;
      float ey = 1.f - wy, ex = 1.f - wx;
      _Float16 w00 = (_Float16)(ey * ex * m * vy0 * vx0);
      _Float16 w01 = (_Float16)(ey * wx * m * vy0 * vx1);
      _Float16 w10 = (_Float16)(wy * ex * m * vy1 * vx0);
      _Float16 w11 = (_Float16)(wy * wx * m * vy1 * vx1);
      h2 W00 = {w00, w00}, W01 = {w01, w01}, W10 = {w10, w10}, W11 = {w11, w11};
      int y0c = min(max(y0, 0), 127) + 1, y1c = min(max(y1, 0), 127) + 1;
      int x0c = min(max(x0, 0), 127) + 1, x1c = min(max(x1, 0), 127) + 1;
      int rb = b * 130;
      h8 v00 = *(const h8*)(Xs + ((size_t)((rb + y0c) * 130 + x0c) << 6) + c8 * 8);
      h8 v01 = *(const h8*)(Xs + ((size_t)((rb + y0c) * 130 + x1c) << 6) + c8 * 8);
      h8 v10 = *(const h8*)(Xs + ((size_t)((rb + y1c) * 130 + x0c) << 6) + c8 * 8);
      h8 v11 = *(const h8*)(Xs + ((size_t)((rb + y1c) * 130 + x1c) << 6) + c8 * 8);
      h8 o;
#pragma unroll
      for (int j2 = 0; j2 < 4; ++j2) {
        h2 a = {v00[2 * j2], v00[2 * j2 + 1]};
        h2 bb = {v01[2 * j2], v01[2 * j2 + 1]};
        h2 cc = {v10[2 * j2], v10[2 * j2 + 1]};
        h2 dd = {v11[2 * j2], v11[2 * j2 + 1]};
        h2 r = a * W00;
        r += bb * W01;
        r += cc * W10;
        r += dd * W11;
        o[2 * j2] = r[0];
        o[2 * j2 + 1] = r[1];
      }
      *(h8*)&S[px * 328 + tl * 64 + c8 * 8] = o;
    }
    __syncthreads();
    // MFMA: wave quadrant (wvM: oc half, wvN: px half), 2 MFMAs per ks
    const int KS = 2 * TAPS;
#pragma unroll
    for (int ks = 0; ks < KS; ++ks) {
      int kg = tap0 * 64 + ks * 32;
      const _Float16* wp = wD + (size_t)(wvM * 32 + lm) * 576 + kg + lq * 8;
      h8 a0 = *(const h8*)(wp);
      h8 a1 = *(const h8*)(wp + 16 * 576);
      h8 bv = *(const h8*)(&S[(wvN * 16 + lm) * 328 + ks * 32 + lq * 8]);
      acc[0] = __builtin_amdgcn_mfma_f32_16x16x32_f16(a0, bv, acc[0], 0, 0, 0);
      acc[1] = __builtin_amdgcn_mfma_f32_16x16x32_f16(a1, bv, acc[1], 0, 0, 0);
    }
  }
  // epilogue: bias + lrelu, fp32 NCHW (wave quadrant)
  int px = pxq0 + wvN * 16 + lm;
#pragma unroll
  for (int mt = 0; mt < 2; ++mt)
#pragma unroll
    for (int r = 0; r < 4; ++r) {
      int oc = wvM * 32 + mt * 16 + lq * 4 + r;
      float v = acc[mt][r] + bd[oc];
      v = (v >= 0.f) ? v : 0.1f * v;
      out[(((b << 6) + oc) << 14) + (y << 7) + px] = v;
    }
}

extern "C" void kernel_launch(void* const* d_in, const int* in_sizes, int n_in,
                              void* d_out, int out_size, void* d_ws, size_t ws_size,
                              hipStream_t stream) {
  const float* nbr   = (const float*)d_in[0];
  const float* refp  = (const float*)d_in[1];
  const float* w1    = (const float*)d_in[2];
  const float* b1    = (const float*)d_in[3];
  const float* w2    = (const float*)d_in[4];
  const float* b2    = (const float*)d_in[5];
  const float* w3    = (const float*)d_in[6];
  const float* b3    = (const float*)d_in[7];
  const float* w_off = (const float*)d_in[8];
  const float* b_off = (const float*)d_in[9];
  const float* w_dcn = (const float*)d_in[10];
  const float* b_dcn = (const float*)d_in[11];

  float* outp = (float*)d_out;
  float* feat = outp;                       // 4*64*16384
  float* offp = outp + 4194304;             // 4*18*16384
  float* mskp = outp + 4194304 + 1179648;   // 4*9*16384

  // ws layout: four padded NHWC f16 buffers [4][130][130][64] + f16 weights (~33.4 MiB)
  char* ws = (char*)d_ws;
  const size_t PB = 8652800;                // bytes per padded buffer
  _Float16* X1  = (_Float16*)ws;            // nbr padded (conv1 in + DCN sample src)
  _Float16* X2  = (_Float16*)(ws + PB);     // ref padded
  _Float16* B64 = (_Float16*)(ws + 2 * PB); // conv1 out / conv3 out
  _Float16* C64 = (_Float16*)(ws + 3 * PB); // conv2 out
  char* p = ws + 4 * PB;
  _Float16* wF1 = (_Float16*)p;  p += (size_t)73728 * 2;
  _Float16* wF2 = (_Float16*)p;  p += (size_t)36864 * 2;
  _Float16* wF3 = (_Float16*)p;  p += (size_t)36864 * 2;
  _Float16* wFo = (_Float16*)p;  p += (size_t)18432 * 2;
  _Float16* wFd = (_Float16*)p;

  // 5 dispatches total
  setup_kernel<<<dim3(3098), 256, 0, stream>>>(nbr, refp, w1, w2, w3, w_off, w_dcn,
                                               X1, X2, B64, C64, wF1, wF2, wF3, wFo, wFd);
  conv3x3_w64_kernel<4, true><<<dim3(512), 128, 0, stream>>>(X1, X2, wF1, b1, B64);
  conv3x3_w64_kernel<2, false><<<dim3(512), 128, 0, stream>>>(B64, nullptr, wF2, b2, C64);
  conv3x3_w64_kernel<2, false><<<dim3(512), 128, 0, stream>>>(C64, nullptr, wF3, b3, B64);
  off_dcn_kernel<<<dim3(2048), 256, 0, stream>>>(B64, X1, wFo, b_off, wFd, b_dcn,
                                                 offp, mskp, feat);
}

// Round 15
// 227.186 us; speedup vs baseline: 1.2625x; 1.0059x over previous
//
#include <hip/hip_runtime.h>
#include <math.h>

// Problem constants: B=4, NF=64, H=W=128, K=9
// d_in order: nbr, ref, w1, b1, w2, b2, w3, b3, w_off, b_off, w_dcn, b_dcn
// d_out: feat [4,64,128,128] | offset [4,18,128,128] | mask [4,9,128,128]

typedef _Float16 h8 __attribute__((ext_vector_type(8)));  // 8 f16 (4 VGPRs)
typedef _Float16 h4 __attribute__((ext_vector_type(4)));  // 4 f16 (2 VGPRs)
typedef _Float16 h2 __attribute__((ext_vector_type(2)));  // packed f16 pair
typedef float f4 __attribute__((ext_vector_type(4)));     // 4 fp32 acc

// ================ merged setup: weight prep + border zero + input prep ================
__global__ __launch_bounds__(256) void setup_kernel(
    const float* __restrict__ nbr, const float* __restrict__ refp,
    const float* __restrict__ w1, const float* __restrict__ w2,
    const float* __restrict__ w3, const float* __restrict__ w_off,
    const float* __restrict__ w_dcn,
    _Float16* __restrict__ X1, _Float16* __restrict__ X2,
    _Float16* __restrict__ B64, _Float16* __restrict__ C64,
    _Float16* __restrict__ wF1, _Float16* __restrict__ wF2,
    _Float16* __restrict__ wF3, _Float16* __restrict__ wFo,
    _Float16* __restrict__ wFd) {
  __shared__ float t[64 * 65];
  int bid = blockIdx.x;
  int tid = threadIdx.x;
  if (bid < 792) {
    int i = bid * 256 + tid;
    if (i < 73728) {                       // w1: NCH=4 (128 IC)
      int j = i;
      int icw = j & 31; int t1 = j >> 5; int oc = t1 & 63; int t2 = t1 >> 6;
      int ch = t2 & 3; int tap = t2 >> 2; int ic = ch * 32 + icw;
      wF1[j] = (_Float16)w1[(oc * 128 + ic) * 9 + tap];
    } else if (i < 110592) {               // w2
      int j = i - 73728;
      int icw = j & 31; int t1 = j >> 5; int oc = t1 & 63; int t2 = t1 >> 6;
      int ch = t2 & 1; int tap = t2 >> 1; int ic = ch * 32 + icw;
      wF2[j] = (_Float16)w2[(oc * 64 + ic) * 9 + tap];
    } else if (i < 147456) {               // w3
      int j = i - 110592;
      int icw = j & 31; int t1 = j >> 5; int oc = t1 & 63; int t2 = t1 >> 6;
      int ch = t2 & 1; int tap = t2 >> 1; int ic = ch * 32 + icw;
      wF3[j] = (_Float16)w3[(oc * 64 + ic) * 9 + tap];
    } else if (i < 165888) {               // w_off padded to 32 oc
      int j = i - 147456;
      int icw = j & 31; int t1 = j >> 5; int oc = t1 & 31; int t2 = t1 >> 5;
      int ch = t2 & 1; int tap = t2 >> 1; int ic = ch * 32 + icw;
      float v = (oc < 27) ? w_off[(oc * 64 + ic) * 9 + tap] : 0.f;
      wFo[j] = (_Float16)v;
    } else if (i < 202752) {               // w_dcn -> [oc][tap*64+c]
      int j = i - 165888;
      int oc = j / 576; int r = j - oc * 576; int tap = r >> 6; int c = r & 63;
      wFd[j] = (_Float16)w_dcn[(oc * 64 + c) * 9 + tap];
    }
    return;
  }
  if (bid < 1050) {
    int i = (bid - 792) * 256 + tid;       // 66048 = 4 buf * 4 b * 516 px * 8 chunks
    int bufi = i / 16512;
    int j = i - bufi * 16512;
    int b = j / 4128;
    int r = j - b * 4128;
    int p = r >> 3; int cg = r & 7;
    int row, col;
    if (p < 130)      { row = 0;   col = p; }
    else if (p < 260) { row = 129; col = p - 130; }
    else if (p < 388) { row = 1 + (p - 260); col = 0; }
    else              { row = 1 + (p - 388); col = 129; }
    _Float16* dst = (bufi == 0) ? X1 : (bufi == 1) ? X2 : (bufi == 2) ? B64 : C64;
    uint4 z; z.x = z.y = z.z = z.w = 0u;
    *(uint4*)(dst + ((size_t)(b * 130 + row) * 130 + col) * 64 + cg * 8) = z;
    return;
  }
  // ---- input prep: fp32 NCHW -> padded NHWC f16 (64-px half-rows)
  int j = bid - 1050;                      // 2048 = 2 src * 4 b * 128 y * 2 half
  int half = j & 1;
  int y = (j >> 1) & 127;
  int b = (j >> 8) & 3;
  int src = j >> 10;
  const float* sp = src ? refp : nbr;
  _Float16* dst = src ? X2 : X1;
  for (int l = tid; l < 64 * 64; l += 256) {
    int c = l >> 6, gx = l & 63;
    t[c * 65 + gx] = sp[(((size_t)b * 64 + c) << 14) + (y << 7) + half * 64 + gx];
  }
  __syncthreads();
  unsigned* dstU = (unsigned*)dst;
  for (int l = tid; l < 64 * 32; l += 256) {
    int pxl = l >> 5, c2 = l & 31;
    union { _Float16 h[2]; unsigned u; } pk;
    pk.h[0] = (_Float16)t[(2 * c2) * 65 + pxl];
    pk.h[1] = (_Float16)t[(2 * c2 + 1) * 65 + pxl];
    dstU[((size_t)(b * 130 + y + 1) * 130 + 1 + half * 64 + pxl) * 32 + c2] = pk.u;
  }
}

// ================ w64 conv: wave tile M=64 x N=64, 2 waves/block, 512 blocks x 128 thr.
// SPLIT: concat of X1 (c<2) and X2 (c>=2) for conv1.
template <int NCH, bool SPLIT>
__global__ __launch_bounds__(128, 1) void conv3x3_w64_kernel(
    const _Float16* __restrict__ X1, const _Float16* __restrict__ X2,
    const _Float16* __restrict__ W, const float* __restrict__ bias,
    _Float16* __restrict__ outP) {
  int tid = threadIdx.x;
  int wv = tid >> 6, L = tid & 63;
  int lm = L & 15, lq = L >> 4;
  int bid = blockIdx.x;                 // 512 = 8 xcd * 16 ystrip * 4 b
  int xcd = bid & 7, j = bid >> 3;
  int y = (xcd << 4) | (j & 15);
  int b = j >> 4;
  int px0 = wv * 64;

  f4 acc[4][4];
#pragma unroll
  for (int i = 0; i < 4; ++i)
#pragma unroll
    for (int n = 0; n < 4; ++n) acc[i][n] = (f4)0.f;

#pragma unroll
  for (int c = 0; c < NCH; ++c) {
    const _Float16* src = (SPLIT && c >= 2) ? X2 : X1;
    int cl = SPLIT ? (c & 1) : c;
#pragma unroll
    for (int tap = 0; tap < 9; ++tap) {
      const int dy = tap / 3 - 1, dx = tap % 3 - 1;
      const _Float16* xb = src + ((size_t)((b * 130 + (y + 1 + dy)) * 130) + (1 + dx) + px0) * 64
                               + cl * 32 + lq * 8;
      h8 b0 = *(const h8*)(xb + lm * 64);
      h8 b1 = *(const h8*)(xb + (16 + lm) * 64);
      h8 b2 = *(const h8*)(xb + (32 + lm) * 64);
      h8 b3 = *(const h8*)(xb + (48 + lm) * 64);
      const _Float16* wp = W + (size_t)((tap * NCH + c) * 64) * 32 + lm * 32 + lq * 8;
      h8 a0 = *(const h8*)(wp);
      h8 a1 = *(const h8*)(wp + 512);
      h8 a2 = *(const h8*)(wp + 1024);
      h8 a3 = *(const h8*)(wp + 1536);
#pragma unroll
      for (int mt = 0; mt < 4; ++mt) {
        h8 am = (mt == 0) ? a0 : (mt == 1) ? a1 : (mt == 2) ? a2 : a3;
        acc[mt][0] = __builtin_amdgcn_mfma_f32_16x16x32_f16(am, b0, acc[mt][0], 0, 0, 0);
        acc[mt][1] = __builtin_amdgcn_mfma_f32_16x16x32_f16(am, b1, acc[mt][1], 0, 0, 0);
        acc[mt][2] = __builtin_amdgcn_mfma_f32_16x16x32_f16(am, b2, acc[mt][2], 0, 0, 0);
        acc[mt][3] = __builtin_amdgcn_mfma_f32_16x16x32_f16(am, b3, acc[mt][3], 0, 0, 0);
      }
    }
  }
  const size_t obase = ((size_t)(b * 130 + (y + 1)) * 130 + 1) * 64;
#pragma unroll
  for (int mt = 0; mt < 4; ++mt)
#pragma unroll
    for (int nt = 0; nt < 4; ++nt) {
      int px = px0 + nt * 16 + lm;
      h4 pk;
#pragma unroll
      for (int r = 0; r < 4; ++r) {
        int oc = mt * 16 + lq * 4 + r;
        float v = acc[mt][nt][r] + bias[oc];
        v = (v >= 0.f) ? v : 0.1f * v;
        pk[r] = (_Float16)v;
      }
      *(h4*)(outP + obase + (size_t)px * 64 + mt * 16 + lq * 4) = pk;
    }
}

// ================ FUSED conv_off + DCN: 4 waves / 32-px block, 3 tap-passes {3,3,3}.
// LDS: S[32][200] f16 (12.8 KB) + Soff[32][28] f32 (3.6 KB) = 16 KB/block ->
// 8 blocks/CU x 4 waves = 32 waves/CU (100% occupancy target; was 75% cap at 2-pass).
// Phase 1 (conv_off): waves 0-1. Phase 2 per pass: sample 3 taps -> S -> MFMA quadrants.
__global__ __launch_bounds__(256, 8) void off_dcn_kernel(
    const _Float16* __restrict__ Xc, const _Float16* __restrict__ Xs,
    const _Float16* __restrict__ Wo, const float* __restrict__ bo,
    const _Float16* __restrict__ wD, const float* __restrict__ bd,
    float* __restrict__ off_out, float* __restrict__ mask_out,
    float* __restrict__ out) {
  __shared__ _Float16 S[32 * 200];
  __shared__ float Soff[32][28];        // per px: [0..17] offsets, [18..26] mask
  int tid = threadIdx.x;
  int wv = tid >> 6, L = tid & 63;
  int lm = L & 15, lq = L >> 4;
  int t8 = L >> 3, c8 = L & 7;
  int g = blockIdx.x;                   // 2048 = 8 xcd * (4 q * 16 ystrip * 4 b)
  int xcd = g & 7;
  int r0 = g >> 3;
  int q = r0 & 3;
  int y = (xcd << 4) | ((r0 >> 2) & 15);
  int b = r0 >> 6;
  int pxq0 = q * 32;

  // ---- phase 1: conv_off for 32 px on waves 0-1 (wave wv covers px half wv)
  if (wv < 2) {
    int px0 = pxq0 + wv * 16;
    f4 oa[2];
    oa[0] = (f4)0.f; oa[1] = (f4)0.f;
#pragma unroll
    for (int c = 0; c < 2; ++c)
#pragma unroll
      for (int tap = 0; tap < 9; ++tap) {
        const int dy = tap / 3 - 1, dx = tap % 3 - 1;
        const _Float16* xb = Xc + ((size_t)((b * 130 + (y + 1 + dy)) * 130) + (1 + dx) + px0) * 64
                                + c * 32 + lq * 8;
        h8 b0 = *(const h8*)(xb + lm * 64);
        const _Float16* wp = Wo + (size_t)((tap * 2 + c) * 32 + lm) * 32 + lq * 8;
        h8 a0 = *(const h8*)(wp);
        h8 a1 = *(const h8*)(wp + 512);
        oa[0] = __builtin_amdgcn_mfma_f32_16x16x32_f16(a0, b0, oa[0], 0, 0, 0);
        oa[1] = __builtin_amdgcn_mfma_f32_16x16x32_f16(a1, b0, oa[1], 0, 0, 0);
      }
    int gpx = px0 + lm;
    int hw = (y << 7) + gpx;
    int lpx = wv * 16 + lm;
#pragma unroll
    for (int mt = 0; mt < 2; ++mt)
#pragma unroll
      for (int r = 0; r < 4; ++r) {
        int oc = mt * 16 + lq * 4 + r;
        if (oc < 18) {
          float v = 15.f * tanhf(oa[mt][r] + bo[oc]);
          off_out[((b * 18 + oc) << 14) + hw] = v;
          Soff[lpx][oc] = v;
        } else if (oc < 27) {
          float v = 1.f / (1.f + expf(-(oa[mt][r] + bo[oc])));
          mask_out[((b * 9 + (oc - 18)) << 14) + hw] = v;
          Soff[lpx][oc] = v;
        }
      }
  }

  // ---- phase 2: DCN, 3 passes of 3 taps
  f4 acc[2];
  acc[0] = (f4)0.f; acc[1] = (f4)0.f;
  int wvM = wv >> 1, wvN = wv & 1;      // MFMA quadrant for this wave

#pragma unroll
  for (int p = 0; p < 3; ++p) {
    const int tap0 = p * 3;
    __syncthreads();                     // covers Soff (p=0) and S reuse (p>0)
    // sampling: 8 lanes per (px, tap) task; 32 tasks per block-iteration (4 waves)
#pragma unroll
    for (int it = 0; it < 3; ++it) {
      int u = it * 32 + wv * 8 + t8;
      int px = u & 31;
      int tl = u >> 5;
      int k = tap0 + tl;
      int wg = pxq0 + px;
      int kr = k / 3;
      float oy = Soff[px][2 * k];
      float ox = Soff[px][2 * k + 1];
      float m = Soff[px][18 + k];
      float py = (float)(y + kr - 1) + oy;
      float pxf = (float)(wg + (k - kr * 3) - 1) + ox;
      float fy = floorf(py), fx = floorf(pxf);
      float wy = py - fy, wx = pxf - fx;
      int y0 = (int)fy, x0 = (int)fx;
      int y1 = y0 + 1, x1 = x0 + 1;
      float vy0 = ((unsigned)y0 < 128u) ? 1.f : 0.f;
      float vy1 = ((unsigned)y1 < 128u) ? 1.f : 0.f;
      float vx0 = ((unsigned)x0 < 128u) ? 1.f : 0.f;
      float vx1 = ((unsigned)x1 < 128u) ? 1.f : 0.f;
      float ey = 1.f - wy, ex = 1.f - wx;
      _Float16 w00 = (_Float16)(ey * ex * m * vy0 * vx0);
      _Float16 w01 = (_Float16)(ey * wx * m * vy0 * vx1);
      _Float16 w10 = (_Float16)(wy * ex * m * vy1 * vx0);
      _Float16 w11 = (_Float16)(wy * wx * m * vy1 * vx1);
      h2 W00 = {w00, w00}, W01 = {w01, w01}, W10 = {w10, w10}, W11 = {w11, w11};
      int y0c = min(max(y0, 0), 127) + 1, y1c = min(max(y1, 0), 127) + 1;
      int x0c = min(max(x0, 0), 127) + 1, x1c = min(max(x1, 0), 127) + 1;
      int rb = b * 130;
      h8 v00 = *(const h8*)(Xs + ((size_t)((rb + y0c) * 130 + x0c) << 6) + c8 * 8);
      h8 v01 = *(const h8*)(Xs + ((size_t)((rb + y0c) * 130 + x1c) << 6) + c8 * 8);
      h8 v10 = *(const h8*)(Xs + ((size_t)((rb + y1c) * 130 + x0c) << 6) + c8 * 8);
      h8 v11 = *(const h8*)(Xs + ((size_t)((rb + y1c) * 130 + x1c) << 6) + c8 * 8);
      h8 o;
#pragma unroll
      for (int j2 = 0; j2 < 4; ++j2) {
        h2 a = {v00[2 * j2], v00[2 * j2 + 1]};
        h2 bb = {v01[2 * j2], v01[2 * j2 + 1]};
        h2 cc = {v10[2 * j2], v10[2 * j2 + 1]};
        h2 dd = {v11[2 * j2], v11[2 * j2 + 1]};
        h2 r = a * W00;
        r += bb * W01;
        r += cc * W10;
        r += dd * W11;
        o[2 * j2] = r[0];
        o[2 * j2 + 1] = r[1];
      }
      *(h8*)&S[px * 200 + tl * 64 + c8 * 8] = o;
    }
    __syncthreads();
    // MFMA: wave quadrant (wvM: oc half, wvN: px half), 2 MFMAs per ks, 6 ks/pass
#pragma unroll
    for (int ks = 0; ks < 6; ++ks) {
      int kg = tap0 * 64 + ks * 32;
      const _Float16* wp = wD + (size_t)(wvM * 32 + lm) * 576 + kg + lq * 8;
      h8 a0 = *(const h8*)(wp);
      h8 a1 = *(const h8*)(wp + 16 * 576);
      h8 bv = *(const h8*)(&S[(wvN * 16 + lm) * 200 + ks * 32 + lq * 8]);
      acc[0] = __builtin_amdgcn_mfma_f32_16x16x32_f16(a0, bv, acc[0], 0, 0, 0);
      acc[1] = __builtin_amdgcn_mfma_f32_16x16x32_f16(a1, bv, acc[1], 0, 0, 0);
    }
  }
  // epilogue: bias + lrelu, fp32 NCHW (wave quadrant)
  int px = pxq0 + wvN * 16 + lm;
#pragma unroll
  for (int mt = 0; mt < 2; ++mt)
#pragma unroll
    for (int r = 0; r < 4; ++r) {
      int oc = wvM * 32 + mt * 16 + lq * 4 + r;
      float v = acc[mt][r] + bd[oc];
      v = (v >= 0.f) ? v : 0.1f * v;
      out[(((b << 6) + oc) << 14) + (y << 7) + px] = v;
    }
}

extern "C" void kernel_launch(void* const* d_in, const int* in_sizes, int n_in,
                              void* d_out, int out_size, void* d_ws, size_t ws_size,
                              hipStream_t stream) {
  const float* nbr   = (const float*)d_in[0];
  const float* refp  = (const float*)d_in[1];
  const float* w1    = (const float*)d_in[2];
  const float* b1    = (const float*)d_in[3];
  const float* w2    = (const float*)d_in[4];
  const float* b2    = (const float*)d_in[5];
  const float* w3    = (const float*)d_in[6];
  const float* b3    = (const float*)d_in[7];
  const float* w_off = (const float*)d_in[8];
  const float* b_off = (const float*)d_in[9];
  const float* w_dcn = (const float*)d_in[10];
  const float* b_dcn = (const float*)d_in[11];

  float* outp = (float*)d_out;
  float* feat = outp;                       // 4*64*16384
  float* offp = outp + 4194304;             // 4*18*16384
  float* mskp = outp + 4194304 + 1179648;   // 4*9*16384

  // ws layout: four padded NHWC f16 buffers [4][130][130][64] + f16 weights (~33.4 MiB)
  char* ws = (char*)d_ws;
  const size_t PB = 8652800;                // bytes per padded buffer
  _Float16* X1  = (_Float16*)ws;            // nbr padded (conv1 in + DCN sample src)
  _Float16* X2  = (_Float16*)(ws + PB);     // ref padded
  _Float16* B64 = (_Float16*)(ws + 2 * PB); // conv1 out / conv3 out
  _Float16* C64 = (_Float16*)(ws + 3 * PB); // conv2 out
  char* p = ws + 4 * PB;
  _Float16* wF1 = (_Float16*)p;  p += (size_t)73728 * 2;
  _Float16* wF2 = (_Float16*)p;  p += (size_t)36864 * 2;
  _Float16* wF3 = (_Float16*)p;  p += (size_t)36864 * 2;
  _Float16* wFo = (_Float16*)p;  p += (size_t)18432 * 2;
  _Float16* wFd = (_Float16*)p;

  // 5 dispatches total
  setup_kernel<<<dim3(3098), 256, 0, stream>>>(nbr, refp, w1, w2, w3, w_off, w_dcn,
                                               X1, X2, B64, C64, wF1, wF2, wF3, wFo, wFd);
  conv3x3_w64_kernel<4, true><<<dim3(512), 128, 0, stream>>>(X1, X2, wF1, b1, B64);
  conv3x3_w64_kernel<2, false><<<dim3(512), 128, 0, stream>>>(B64, nullptr, wF2, b2, C64);
  conv3x3_w64_kernel<2, false><<<dim3(512), 128, 0, stream>>>(C64, nullptr, wF3, b3, B64);
  off_dcn_kernel<<<dim3(2048), 256, 0, stream>>>(B64, X1, wFo, b_off, wFd, b_dcn,
                                                 offp, mskp, feat);
}